// Round 8
// baseline (872.387 us; speedup 1.0000x reference)
//
#include <hip/hip_runtime.h>
#include <stdint.h>

// PyramidAttention gfx950 — round 8: R7 + B-swizzle wraparound fix.
// 36 segments/col is a multiple of 4 not 8 -> XOR-4 swizzle over (col>>1)&3
// (same pattern as R5's conflict-free Rs layout), in k_bs AND k_attn.
// B via global_load_lds dbuf (41 KB LDS), R direct global->VGPR, static
// row-max softmax, deferred row-sums, one barrier/chunk, 3 blocks/CU.

typedef __attribute__((ext_vector_type(8))) short bf16x8;
typedef __attribute__((ext_vector_type(4))) float f32x4;
typedef unsigned short ushort_t;

#define L_TOT  13326
#define NCHT   417        // 32-l chunks (padded to 13344)
#define NPIX   4096
#define NSPL   3
#define CH_PER 139        // 417 / 3
#define BCHUNK_E 9216     // 32 cols * 288 k
#define RCHUNK_E 18432    // 576 cols * 32 l
#define LOG2E10 14.4269504f   // 10*log2(e)

__device__ __forceinline__ float cubw(float d) {
  d = fabsf(d);
  if (d <= 1.f) return (1.25f * d - 2.25f) * d * d + 1.f;          // A=-0.75
  if (d < 2.f)  return ((-0.75f * d + 3.75f) * d - 6.f) * d + 3.f;
  return 0.f;
}

__device__ __forceinline__ void decode_l(int l, int& S, int& off) {
  if (l < 4096)       { S = 64; off = 0; }
  else if (l < 7345)  { S = 57; off = 4096; }
  else if (l < 9946)  { S = 51; off = 7345; }
  else if (l < 11882) { S = 44; off = 9946; }
  else                { S = 38; off = 11882; }
}

__device__ __forceinline__ ushort_t f2bf(float f) {
  union { float f; uint32_t u; } v; v.f = f;
  uint32_t r = (v.u + 0x7fffu + ((v.u >> 16) & 1u)) >> 16;  // RNE
  return (ushort_t)r;
}

__device__ __forceinline__ float preluf(float x, float a) { return x >= 0.f ? x : a * x; }

__device__ __forceinline__ void gll16(const ushort_t* g, ushort_t* l) {
  __builtin_amdgcn_global_load_lds(
      (const __attribute__((address_space(1))) unsigned int*)g,
      (__attribute__((address_space(3))) unsigned int*)l, 16, 0, 0);
}

// ---------------- K1: bicubic resize (align_corners=True, border clamp) ----------------
__global__ void k_resize(const float* __restrict__ inref, float* __restrict__ refbuf, int n) {
  int idx = blockIdx.x * 256 + threadIdx.x;
  if (idx >= n) return;                      // n = 2*64*L_TOT, idx -> (b*64+c, l)
  int l = idx % L_TOT; int bc = idx / L_TOT;
  int S, off; decode_l(l, S, off);
  int li = l - off; int ly = li / S, lx = li % S;
  float val;
  if (S == 64) {
    val = inref[(size_t)bc * 4096 + ly * 64 + lx];
  } else {
    float sc = (float)(63.0 / (double)(S - 1));
    float sy = (float)ly * sc, sx = (float)lx * sc;
    int iy = (int)floorf(sy), ix = (int)floorf(sx);
    float fy = sy - (float)iy, fx = sx - (float)ix;
    float wy[4] = { cubw(fy + 1.f), cubw(fy), cubw(1.f - fy), cubw(2.f - fy) };
    float wx[4] = { cubw(fx + 1.f), cubw(fx), cubw(1.f - fx), cubw(2.f - fx) };
    val = 0.f;
    for (int t = 0; t < 4; ++t) {
      int ty = iy - 1 + t; ty = ty < 0 ? 0 : (ty > 63 ? 63 : ty);
      float rv = 0.f;
      for (int u = 0; u < 4; ++u) {
        int tx = ix - 1 + u; tx = tx < 0 ? 0 : (tx > 63 ? 63 : tx);
        rv += wx[u] * inref[(size_t)bc * 4096 + ty * 64 + tx];
      }
      val += wy[t] * rv;
    }
  }
  refbuf[(size_t)bc * L_TOT + l] = val;
}

// ---------------- K2: conv1x1 (Wm->mref 32ch, Wa->aref 64ch) + prelu ----------------
__global__ void k_convref(const float* __restrict__ refbuf,
                          const float* __restrict__ Wm, const float* __restrict__ bm,
                          const float* __restrict__ Wa, const float* __restrict__ ba,
                          const float* __restrict__ ap,
                          float* __restrict__ mref, float* __restrict__ aref, int n) {
  int idx = blockIdx.x * 256 + threadIdx.x;
  if (idx >= n) return;                      // n = 2*96*L_TOT
  int l = idx % L_TOT; int ch = (idx / L_TOT) % 96; int b = idx / (96 * L_TOT);
  float a = ap[0];
  const float* base = refbuf + (size_t)b * 64 * L_TOT + l;
  const float* Wrow; float acc;
  if (ch < 32) { Wrow = Wm + ch * 64; acc = bm[ch]; }
  else         { Wrow = Wa + (ch - 32) * 64; acc = ba[ch - 32]; }
  for (int c = 0; c < 64; ++c) acc += Wrow[c] * base[(size_t)c * L_TOT];
  acc = preluf(acc, a);
  if (ch < 32) mref[(size_t)(b * 32 + ch) * L_TOT + l] = acc;
  else         aref[(size_t)(b * 64 + ch - 32) * L_TOT + l] = acc;
}

// ---------------- K3: match_base = prelu(Wb@input+bb) ----------------
__global__ void k_mb(const float* __restrict__ input, const float* __restrict__ Wb,
                     const float* __restrict__ bb, const float* __restrict__ ap,
                     float* __restrict__ mbb, int n) {
  int idx = blockIdx.x * 256 + threadIdx.x;
  if (idx >= n) return;                      // n = 2*32*NPIX
  int p = idx % NPIX; int cm = (idx / NPIX) % 32; int b = idx / (32 * NPIX);
  float a = ap[0];
  float acc = bb[cm];
  for (int c = 0; c < 64; ++c) acc += Wb[cm * 64 + c] * input[(size_t)(b * 64 + c) * NPIX + p];
  mbb[(size_t)(b * 32 + cm) * NPIX + p] = preluf(acc, a);
}

// ---------------- K4a: per-position sum of squares of mref (key side) ----------------
__global__ void k_ssq(const float* __restrict__ mref, float* __restrict__ ssq, int n) {
  int idx = blockIdx.x * 256 + threadIdx.x;
  if (idx >= n) return;                      // n = 2*L_TOT
  int l = idx % L_TOT; int b = idx / L_TOT;
  float s = 0.f;
  for (int c = 0; c < 32; ++c) { float v = mref[(size_t)(b * 32 + c) * L_TOT + l]; s += v * v; }
  ssq[idx] = s;
}

// ---------------- K4b: 3x3 window sum -> 1/max(sqrt, 1e-4) (key norm) ----------------
__global__ void k_invn(const float* __restrict__ ssq, float* __restrict__ invn, int n) {
  int idx = blockIdx.x * 256 + threadIdx.x;
  if (idx >= n) return;
  int l = idx % L_TOT; int b = idx / L_TOT;
  int S, off; decode_l(l, S, off);
  int li = l - off; int ly = li / S, lx = li % S;
  float acc = 0.f;
  for (int dy = -1; dy <= 1; ++dy) {
    int ny = ly + dy; if (ny < 0 || ny >= S) continue;
    for (int dx = -1; dx <= 1; ++dx) {
      int nx = lx + dx; if (nx < 0 || nx >= S) continue;
      acc += ssq[(size_t)b * L_TOT + off + ny * S + nx];
    }
  }
  float nrm = sqrtf(acc); nrm = fmaxf(nrm, 1e-4f);
  invn[idx] = 1.f / nrm;
}

// ---------------- K4c: per-pixel channel ssq of match_base (query side) ----------------
__global__ void k_ssqA(const float* __restrict__ mbb, float* __restrict__ ssqA, int n) {
  int idx = blockIdx.x * 256 + threadIdx.x;
  if (idx >= n) return;                      // n = 2*NPIX
  int p = idx % NPIX; int b = idx / NPIX;
  float s = 0.f;
  for (int c = 0; c < 32; ++c) { float v = mbb[(size_t)(b * 32 + c) * NPIX + p]; s += v * v; }
  ssqA[idx] = s;
}

// ---------------- K4d: 3x3 window (zero-pad) -> static log2-domain row max ----------------
__global__ void k_m10(const float* __restrict__ ssqA, float* __restrict__ Mlog, int n) {
  int idx = blockIdx.x * 256 + threadIdx.x;
  if (idx >= n) return;                      // n = 2*NPIX
  int p = idx % NPIX; int b = idx / NPIX;
  int y = p / 64, x = p % 64;
  float acc = 0.f;
  for (int dy = -1; dy <= 1; ++dy) {
    int ny = y + dy; if (ny < 0 || ny >= 64) continue;
    for (int dx = -1; dx <= 1; ++dx) {
      int nx = x + dx; if (nx < 0 || nx >= 64) continue;
      acc += ssqA[(size_t)b * NPIX + ny * 64 + nx];
    }
  }
  float qn = sqrtf(acc);
  float m = fmaxf(0.7f * qn, qn - 7.f);
  Mlog[idx] = LOG2E10 * m;
}

// ---------------- K5: B patches -> pre-swizzled LDS-image chunks ----------------
// Bs[b][ch][slot]: slot = col*288 + segp*8 + e, 36 segs/col.
// XOR-4 swizzle: segl = (segp&~3) | ((segp&3) ^ ((col>>1)&3)); k = segl*8+e.
__global__ void k_bs(const float* __restrict__ mref, const float* __restrict__ invn,
                     ushort_t* __restrict__ Bs, int n) {
  int idx = blockIdx.x * 256 + threadIdx.x;
  if (idx >= n) return;                      // n = 2*NCHT*BCHUNK_E
  int slot = idx % BCHUNK_E; int ch = (idx / BCHUNK_E) % NCHT; int b = idx / (BCHUNK_E * NCHT);
  int col = slot / 288; int rem = slot % 288; int segp = rem >> 3; int e = rem & 7;
  int segl = (segp & ~3) | ((segp & 3) ^ ((col >> 1) & 3));
  int k = segl * 8 + e;
  int l = ch * 32 + col;
  float v = 0.f;
  if (l < L_TOT) {
    int c = k / 9; int r = k % 9; int dy = r / 3 - 1, dx = r % 3 - 1;
    int S, off; decode_l(l, S, off);
    int li = l - off; int ly = li / S, lx = li % S;
    int ny = ly + dy, nx = lx + dx;
    if (ny >= 0 && ny < S && nx >= 0 && nx < S)
      v = mref[(size_t)(b * 32 + c) * L_TOT + off + ny * S + nx] * invn[(size_t)b * L_TOT + l];
  }
  Bs[idx] = f2bf(v);
}

// ---------------- K6: A im2col (query patches) bf16 [b][p][288] ----------------
__global__ void k_aim(const float* __restrict__ mbb, ushort_t* __restrict__ Am, int n) {
  int idx = blockIdx.x * 256 + threadIdx.x;
  if (idx >= n) return;                      // n = 2*NPIX*288
  int k = idx % 288; int p = (idx / 288) % NPIX; int b = idx / (288 * NPIX);
  int c = k / 9; int r = k % 9; int dy = r / 3 - 1, dx = r % 3 - 1;
  int y = p / 64, x = p % 64;
  int ny = y + dy, nx = x + dx;
  float v = 0.f;
  if (ny >= 0 && ny < 64 && nx >= 0 && nx < 64)
    v = mbb[(size_t)(b * 32 + c) * NPIX + ny * 64 + nx];
  Am[(size_t)(b * NPIX + p) * 288 + k] = f2bf(v);
}

// ---------------- K7: R value patches, plain chunk layout [b][ch][col*32+lo] ----------------
__global__ void k_rs(const float* __restrict__ aref, ushort_t* __restrict__ Rs, int n) {
  int idx = blockIdx.x * 256 + threadIdx.x;
  if (idx >= n) return;                      // n = 2*NCHT*RCHUNK_E
  int slot = idx % RCHUNK_E; int ch = (idx / RCHUNK_E) % NCHT; int b = idx / (RCHUNK_E * NCHT);
  int col = slot >> 5; int lo = slot & 31;
  int l = ch * 32 + lo;
  float v = 0.f;
  if (l < L_TOT) {
    int c = col / 9; int r = col % 9; int dy = r / 3 - 1, dx = r % 3 - 1;
    int S, off; decode_l(l, S, off);
    int li = l - off; int ly = li / S, lx = li % S;
    int ny = ly + dy, nx = lx + dx;
    if (ny >= 0 && ny < S && nx >= 0 && nx < S)
      v = aref[(size_t)(b * 64 + c) * L_TOT + off + ny * S + nx];
  }
  Rs[idx] = f2bf(v);
}

// ---------------- K8: fused attention, 3 blocks/CU ----------------
// grid 768: blockIdx -> tile(0..127) | spl(0..2) | b(0..1). 256 thr = 4 waves.
// S: wave(rb,cbh) = 16 rows x 16 cols (B frags from LDS dbuf).
// Z: wave owns 144 cols x 32 rows (R frags from global, reloaded in place).
__global__ __launch_bounds__(256, 3) void k_attn(const ushort_t* __restrict__ Am,
                                                 const ushort_t* __restrict__ Bs,
                                                 const ushort_t* __restrict__ Rs,
                                                 const float* __restrict__ Mlog,
                                                 float* __restrict__ Og,
                                                 float* __restrict__ Ol) {
  __shared__ ushort_t Bl[2][BCHUNK_E];   // 36864 B dbuf B chunk (swizzled image)
  __shared__ ushort_t Pl[2][1024];       // 4096 B dbuf P tile (swizzled)
  int tid = threadIdx.x;
  int tile = blockIdx.x & 127;
  int spl = (blockIdx.x >> 7) % 3;
  int b = blockIdx.x / 384;
  int p0 = tile * 32;
  int wave = tid >> 6, lane = tid & 63, quad = lane >> 4, ln = lane & 15;
  int rb = wave & 1, cbh = wave >> 1;
  int c0 = spl * CH_PER, c1 = c0 + CH_PER;

  // A fragments resident; static row-max (log2 domain)
  bf16x8 af[9];
  {
    const ushort_t* arow = Am + (size_t)(b * NPIX + p0 + rb * 16 + ln) * 288;
    #pragma unroll
    for (int kk = 0; kk < 9; ++kk) af[kk] = *(const bf16x8*)(arow + kk * 32 + quad * 8);
  }
  float mlg[4];
  #pragma unroll
  for (int r = 0; r < 4; ++r)
    mlg[r] = Mlog[(size_t)b * NPIX + p0 + rb * 16 + quad * 4 + r];

  f32x4 acc[2][9];
  #pragma unroll
  for (int h = 0; h < 2; ++h)
    #pragma unroll
    for (int t = 0; t < 9; ++t) { acc[h][t][0] = acc[h][t][1] = acc[h][t][2] = acc[h][t][3] = 0.f; }
  float psum[4] = {0.f, 0.f, 0.f, 0.f};

  const ushort_t* BsB = Bs + (size_t)b * NCHT * BCHUNK_E;
  const ushort_t* RsB = Rs + (size_t)b * NCHT * RCHUNK_E
                        + (size_t)(wave * 144 + ln) * 32 + quad * 8;
  int col32 = cbh * 16 + ln;
  int bswz = (col32 >> 1) & 3;

  // prologue: stage B chunk c0, load R frags c0
  {
    const ushort_t* src = BsB + (size_t)c0 * BCHUNK_E;
    ushort_t* dst = Bl[c0 & 1];
    #pragma unroll
    for (int i = 0; i < 4; ++i) {
      int slab = wave + i * 4;
      gll16(src + slab * 512 + lane * 8, dst + slab * 512);
    }
    if (wave < 2) {
      int slab = 16 + wave;
      gll16(src + slab * 512 + lane * 8, dst + slab * 512);
    }
  }
  bf16x8 rcur[9];
  {
    const ushort_t* rsrc = RsB + (size_t)c0 * RCHUNK_E;
    #pragma unroll
    for (int t = 0; t < 9; ++t) rcur[t] = *(const bf16x8*)(rsrc + t * 512);
  }
  __syncthreads();   // drain prologue DMA before first S-MFMA reads Bl

  for (int ch = c0; ch < c1; ++ch) {
    int par = ch & 1;
    int cp = ch + 1 < NCHT ? ch + 1 : NCHT - 1;
    // stage next B chunk into other buffer (async DMA, drained at barrier)
    {
      const ushort_t* src = BsB + (size_t)cp * BCHUNK_E;
      ushort_t* dst = Bl[par ^ 1];
      #pragma unroll
      for (int i = 0; i < 4; ++i) {
        int slab = wave + i * 4;
        gll16(src + slab * 512 + lane * 8, dst + slab * 512);
      }
      if (wave < 2) {
        int slab = 16 + wave;
        gll16(src + slab * 512 + lane * 8, dst + slab * 512);
      }
    }
    // S-MFMA from LDS B frags (two independent chains); XOR-4 swizzle
    f32x4 sa, sb;
    sa[0] = sa[1] = sa[2] = sa[3] = 0.f;
    sb[0] = sb[1] = sb[2] = sb[3] = 0.f;
    #pragma unroll
    for (int kk = 0; kk < 9; ++kk) {
      int segp = kk * 4 + (quad ^ bswz);
      bf16x8 bf = *(const bf16x8*)&Bl[par][col32 * 288 + segp * 8];
      if (kk & 1) sb = __builtin_amdgcn_mfma_f32_16x16x32_bf16(af[kk], bf, sb, 0, 0, 0);
      else        sa = __builtin_amdgcn_mfma_f32_16x16x32_bf16(af[kk], bf, sa, 0, 0, 0);
    }
    // P = 2^(14.43*s - Mlog) (padding cols: B rows zero -> pv underflows to 0)
    #pragma unroll
    for (int r = 0; r < 4; ++r) {
      float sv = sa[r] + sb[r];
      float pv = exp2f(fmaf(sv, LOG2E10, -mlg[r]));
      int row = rb * 16 + quad * 4 + r;
      int seg = cbh * 2 + (ln >> 3);
      int swz = seg ^ ((row >> 1) & 3);
      Pl[par][row * 32 + swz * 8 + (ln & 7)] = f2bf(pv);
      psum[r] += pv;
    }
    __syncthreads();   // P ready + next-B DMA drained (only barrier per chunk)
    // Z-GEMM: P(32x32) @ R(32 x 144-per-wave); reload R frag right after use
    bf16x8 pf0, pf1;
    {
      int sw0 = quad ^ ((ln >> 1) & 3);
      int sw1 = quad ^ (((16 + ln) >> 1) & 3);
      pf0 = *(const bf16x8*)&Pl[par][ln * 32 + sw0 * 8];
      pf1 = *(const bf16x8*)&Pl[par][(16 + ln) * 32 + sw1 * 8];
    }
    const ushort_t* rsrc = RsB + (size_t)cp * RCHUNK_E;
    #pragma unroll
    for (int t = 0; t < 9; ++t) {
      acc[0][t] = __builtin_amdgcn_mfma_f32_16x16x32_bf16(pf0, rcur[t], acc[0][t], 0, 0, 0);
      acc[1][t] = __builtin_amdgcn_mfma_f32_16x16x32_bf16(pf1, rcur[t], acc[1][t], 0, 0, 0);
      rcur[t] = *(const bf16x8*)(rsrc + t * 512);
    }
  }

  // epilogue: reduce deferred row-sums over 16 lanes, write stats + O
  #pragma unroll
  for (int m = 1; m <= 8; m <<= 1)
    #pragma unroll
    for (int r = 0; r < 4; ++r) psum[r] += __shfl_xor(psum[r], m);
  int sb2 = spl * 2 + b;
  if (ln == 0) {
    #pragma unroll
    for (int r = 0; r < 4; ++r) {
      int row = p0 + rb * 16 + quad * 4 + r;
      Ol[(size_t)(sb2 * 2 + cbh) * NPIX + row] = psum[r];
    }
  }
  #pragma unroll
  for (int h = 0; h < 2; ++h)
    #pragma unroll
    for (int t = 0; t < 9; ++t) {
      int colg = wave * 144 + t * 16 + ln;
      #pragma unroll
      for (int r = 0; r < 4; ++r) {
        int row = p0 + h * 16 + quad * 4 + r;
        Og[((size_t)sb2 * NPIX + row) * 576 + colg] = acc[h][t][r];
      }
    }
}

// ---------------- K9: inv = 1 / sum of 6 partial row-sums ----------------
__global__ void k_inv(const float* __restrict__ Ol, float* __restrict__ inv, int n) {
  int idx = blockIdx.x * 256 + threadIdx.x;
  if (idx >= n) return;                      // n = 2*NPIX; idx = b*NPIX+p
  int b = idx / NPIX; int p = idx % NPIX;
  float s = 0.f;
  #pragma unroll
  for (int spl = 0; spl < NSPL; ++spl)
    #pragma unroll
    for (int cbh = 0; cbh < 2; ++cbh)
      s += Ol[(size_t)((spl * 2 + b) * 2 + cbh) * NPIX + p];
  inv[idx] = 1.f / s;
}

// ---------------- K10: 9-tap gather, split-sum, *inv, /4, + residual ----------------
__global__ void k_final(const float* __restrict__ Og, const float* __restrict__ inv,
                        const float* __restrict__ input, float* __restrict__ out, int n) {
  int idx = blockIdx.x * 256 + threadIdx.x;
  if (idx >= n) return;                      // n = 2*64*NPIX, idx = ((b*64+c)*64+y)*64+x
  int x = idx & 63; int y = (idx >> 6) & 63; int c = (idx >> 12) & 63; int b = idx >> 18;
  const size_t S1 = (size_t)2 * NPIX * 576;
  float acc = 0.f;
  for (int j = 0; j < 3; ++j) {
    int qy = y + 1 - j; if (qy < 0 || qy >= 64) continue;
    for (int i = 0; i < 3; ++i) {
      int qx = x + 1 - i; if (qx < 0 || qx >= 64) continue;
      int p = qy * 64 + qx;
      size_t e = ((size_t)b * NPIX + p) * 576 + c * 9 + j * 3 + i;
      float z = (Og[e] + Og[e + S1] + Og[e + 2 * S1]) * inv[b * NPIX + p];
      acc += z;
    }
  }
  out[idx] = 0.25f * acc + input[idx];
}

extern "C" void kernel_launch(void* const* d_in, const int* in_sizes, int n_in,
                              void* d_out, int out_size, void* d_ws, size_t ws_size,
                              hipStream_t stream) {
  (void)in_sizes; (void)n_in; (void)out_size; (void)ws_size;
  const float* input = (const float*)d_in[0];
  const float* inref = (const float*)d_in[1];
  const float* Wb = (const float*)d_in[2];
  const float* bb = (const float*)d_in[3];
  const float* Wm = (const float*)d_in[4];
  const float* bm = (const float*)d_in[5];
  const float* Wa = (const float*)d_in[6];
  const float* ba = (const float*)d_in[7];
  const float* ap = (const float*)d_in[8];
  float* out = (float*)d_out;

  char* ws = (char*)d_ws;
  size_t off = 0;
  auto alloc = [&](size_t bytes) -> char* {
    char* p = ws + off; off = (off + bytes + 255) & ~(size_t)255; return p;
  };
  // persistent region
  ushort_t* Am   = (ushort_t*)alloc((size_t)2 * NPIX * 288 * 2);         // 4.7 MB
  ushort_t* Bs   = (ushort_t*)alloc((size_t)2 * NCHT * BCHUNK_E * 2);    // 15.4 MB
  ushort_t* Rs   = (ushort_t*)alloc((size_t)2 * NCHT * RCHUNK_E * 2);    // 30.7 MB
  float*    Ol   = (float*)alloc((size_t)12 * NPIX * 4);
  float*    inv  = (float*)alloc((size_t)2 * NPIX * 4);
  float*    Mlog = (float*)alloc((size_t)2 * NPIX * 4);
  float*    ssqA = (float*)alloc((size_t)2 * NPIX * 4);
  // big region: Og (56.6 MB) aliases early prep buffers (dead before k_attn)
  size_t og_bytes = (size_t)NSPL * 2 * NPIX * 576 * 4;
  char* big = alloc(og_bytes);
  float* Og = (float*)big;
  size_t eoff = 0;
  auto ealloc = [&](size_t bytes) -> char* {
    char* p = big + eoff; eoff = (eoff + bytes + 255) & ~(size_t)255; return p;
  };
  float* refbuf = (float*)ealloc((size_t)2 * 64 * L_TOT * 4);
  float* mref   = (float*)ealloc((size_t)2 * 32 * L_TOT * 4);
  float* aref   = (float*)ealloc((size_t)2 * 64 * L_TOT * 4);
  float* mbb    = (float*)ealloc((size_t)2 * 32 * NPIX * 4);
  float* ssq    = (float*)ealloc((size_t)2 * L_TOT * 4);
  float* invn   = (float*)ealloc((size_t)2 * L_TOT * 4);
  // total ws ~ 108 MB

  int n1 = 2 * 64 * L_TOT;
  k_resize<<<(n1 + 255) / 256, 256, 0, stream>>>(inref, refbuf, n1);
  int n2 = 2 * 96 * L_TOT;
  k_convref<<<(n2 + 255) / 256, 256, 0, stream>>>(refbuf, Wm, bm, Wa, ba, ap, mref, aref, n2);
  int n3 = 2 * 32 * NPIX;
  k_mb<<<(n3 + 255) / 256, 256, 0, stream>>>(input, Wb, bb, ap, mbb, n3);
  int n4 = 2 * L_TOT;
  k_ssq<<<(n4 + 255) / 256, 256, 0, stream>>>(mref, ssq, n4);
  k_invn<<<(n4 + 255) / 256, 256, 0, stream>>>(ssq, invn, n4);
  int n4a = 2 * NPIX;
  k_ssqA<<<(n4a + 255) / 256, 256, 0, stream>>>(mbb, ssqA, n4a);
  k_m10<<<(n4a + 255) / 256, 256, 0, stream>>>(ssqA, Mlog, n4a);
  int n5 = 2 * NCHT * BCHUNK_E;
  k_bs<<<(n5 + 255) / 256, 256, 0, stream>>>(mref, invn, Bs, n5);
  int n6 = 2 * NPIX * 288;
  k_aim<<<(n6 + 255) / 256, 256, 0, stream>>>(mbb, Am, n6);
  int n7 = 2 * NCHT * RCHUNK_E;
  k_rs<<<(n7 + 255) / 256, 256, 0, stream>>>(aref, Rs, n7);

  k_attn<<<768, 256, 0, stream>>>(Am, Bs, Rs, Mlog, Og, Ol);
  k_inv<<<(2 * NPIX + 255) / 256, 256, 0, stream>>>(Ol, inv, 2 * NPIX);
  int no = 2 * 64 * NPIX;
  k_final<<<(no + 255) / 256, 256, 0, stream>>>(Og, inv, input, out, no);
}

// Round 9
// 692.147 us; speedup vs baseline: 1.2604x; 1.2604x over previous
//
#include <hip/hip_runtime.h>
#include <stdint.h>

// PyramidAttention gfx950 — round 9: k_attn reverted to the proven R5 structure
// (R via global_load_lds dbuf consumed AFTER the barrier, B direct-reg with
// one-chunk prefetch, static row-max, deferred row-sums, 2 blocks/CU).
// New: LDS-tiled k_convref (refbuf read once, not 96x) and c-fastest k_final
// (tap reads lane-stride 36 B instead of 2304 B; LDS transpose for writes).

typedef __attribute__((ext_vector_type(8))) short bf16x8;
typedef __attribute__((ext_vector_type(4))) float f32x4;
typedef unsigned short ushort_t;

#define L_TOT  13326
#define L_PADB 13344   // 417 chunks * 32
#define NCHT   417
#define NPIX   4096
#define RCHUNK_E 18432 // 576 cols * 32 l
#define LOG2E10 14.4269504f   // 10*log2(e)
#define CT 256         // k_convref l-tile

__device__ __forceinline__ float cubw(float d) {
  d = fabsf(d);
  if (d <= 1.f) return (1.25f * d - 2.25f) * d * d + 1.f;          // A=-0.75
  if (d < 2.f)  return ((-0.75f * d + 3.75f) * d - 6.f) * d + 3.f;
  return 0.f;
}

__device__ __forceinline__ void decode_l(int l, int& S, int& off) {
  if (l < 4096)       { S = 64; off = 0; }
  else if (l < 7345)  { S = 57; off = 4096; }
  else if (l < 9946)  { S = 51; off = 7345; }
  else if (l < 11882) { S = 44; off = 9946; }
  else                { S = 38; off = 11882; }
}

__device__ __forceinline__ ushort_t f2bf(float f) {
  union { float f; uint32_t u; } v; v.f = f;
  uint32_t r = (v.u + 0x7fffu + ((v.u >> 16) & 1u)) >> 16;  // RNE
  return (ushort_t)r;
}

__device__ __forceinline__ float preluf(float x, float a) { return x >= 0.f ? x : a * x; }

__device__ __forceinline__ void gll16(const ushort_t* g, ushort_t* l) {
  __builtin_amdgcn_global_load_lds(
      (const __attribute__((address_space(1))) unsigned int*)g,
      (__attribute__((address_space(3))) unsigned int*)l, 16, 0, 0);
}

// ---------------- K1: bicubic resize (align_corners=True, border clamp) ----------------
__global__ void k_resize(const float* __restrict__ inref, float* __restrict__ refbuf, int n) {
  int idx = blockIdx.x * 256 + threadIdx.x;
  if (idx >= n) return;                      // n = 2*64*L_TOT, idx -> (b*64+c, l)
  int l = idx % L_TOT; int bc = idx / L_TOT;
  int S, off; decode_l(l, S, off);
  int li = l - off; int ly = li / S, lx = li % S;
  float val;
  if (S == 64) {
    val = inref[(size_t)bc * 4096 + ly * 64 + lx];
  } else {
    float sc = (float)(63.0 / (double)(S - 1));
    float sy = (float)ly * sc, sx = (float)lx * sc;
    int iy = (int)floorf(sy), ix = (int)floorf(sx);
    float fy = sy - (float)iy, fx = sx - (float)ix;
    float wy[4] = { cubw(fy + 1.f), cubw(fy), cubw(1.f - fy), cubw(2.f - fy) };
    float wx[4] = { cubw(fx + 1.f), cubw(fx), cubw(1.f - fx), cubw(2.f - fx) };
    val = 0.f;
    for (int t = 0; t < 4; ++t) {
      int ty = iy - 1 + t; ty = ty < 0 ? 0 : (ty > 63 ? 63 : ty);
      float rv = 0.f;
      for (int u = 0; u < 4; ++u) {
        int tx = ix - 1 + u; tx = tx < 0 ? 0 : (tx > 63 ? 63 : tx);
        rv += wx[u] * inref[(size_t)bc * 4096 + ty * 64 + tx];
      }
      val += wy[t] * rv;
    }
  }
  refbuf[(size_t)bc * L_TOT + l] = val;
}

// ---------------- K2: conv1x1 + prelu, LDS-tiled (refbuf read ONCE) ----------------
// grid: b(2) x ltile(53) x ochalf(2) = 212 blocks, 256 threads.
__global__ void k_convref(const float* __restrict__ refbuf,
                          const float* __restrict__ Wm, const float* __restrict__ bm,
                          const float* __restrict__ Wa, const float* __restrict__ ba,
                          const float* __restrict__ ap,
                          float* __restrict__ mref, float* __restrict__ aref) {
  __shared__ float T[64][CT];   // 64 KB tile: 64 in-ch x 256 l
  int blk = blockIdx.x;
  int oh = blk & 1; int lt = (blk >> 1) % 53; int b = blk / 106;
  int l0 = lt * CT;
  int tid = threadIdx.x;
  float a = ap[0];
  for (int i = tid; i < 64 * CT; i += 256) {
    int c = i >> 8; int l = i & 255;          // consecutive tid -> consecutive l (coalesced)
    int gl = l0 + l;
    T[c][l] = (gl < L_TOT) ? refbuf[(size_t)(b * 64 + c) * L_TOT + gl] : 0.f;
  }
  __syncthreads();
  int gl = l0 + tid;
  if (gl >= L_TOT) return;
  for (int oc = oh * 48; oc < oh * 48 + 48; ++oc) {
    const float* Wrow; float s;
    if (oc < 32) { Wrow = Wm + oc * 64; s = bm[oc]; }
    else         { Wrow = Wa + (oc - 32) * 64; s = ba[oc - 32]; }
    #pragma unroll 8
    for (int c = 0; c < 64; ++c) s += Wrow[c] * T[c][tid];
    s = preluf(s, a);
    if (oc < 32) mref[(size_t)(b * 32 + oc) * L_TOT + gl] = s;
    else         aref[(size_t)(b * 64 + oc - 32) * L_TOT + gl] = s;
  }
}

// ---------------- K3: match_base = prelu(Wb@input+bb) ----------------
__global__ void k_mb(const float* __restrict__ input, const float* __restrict__ Wb,
                     const float* __restrict__ bb, const float* __restrict__ ap,
                     float* __restrict__ mbb, int n) {
  int idx = blockIdx.x * 256 + threadIdx.x;
  if (idx >= n) return;                      // n = 2*32*NPIX
  int p = idx % NPIX; int cm = (idx / NPIX) % 32; int b = idx / (32 * NPIX);
  float a = ap[0];
  float acc = bb[cm];
  for (int c = 0; c < 64; ++c) acc += Wb[cm * 64 + c] * input[(size_t)(b * 64 + c) * NPIX + p];
  mbb[(size_t)(b * 32 + cm) * NPIX + p] = preluf(acc, a);
}

// ---------------- K4a: per-position sum of squares of mref (key side) ----------------
__global__ void k_ssq(const float* __restrict__ mref, float* __restrict__ ssq, int n) {
  int idx = blockIdx.x * 256 + threadIdx.x;
  if (idx >= n) return;                      // n = 2*L_TOT
  int l = idx % L_TOT; int b = idx / L_TOT;
  float s = 0.f;
  for (int c = 0; c < 32; ++c) { float v = mref[(size_t)(b * 32 + c) * L_TOT + l]; s += v * v; }
  ssq[idx] = s;
}

// ---------------- K4b: 3x3 window sum -> 1/max(sqrt, 1e-4) (key norm) ----------------
__global__ void k_invn(const float* __restrict__ ssq, float* __restrict__ invn, int n) {
  int idx = blockIdx.x * 256 + threadIdx.x;
  if (idx >= n) return;
  int l = idx % L_TOT; int b = idx / L_TOT;
  int S, off; decode_l(l, S, off);
  int li = l - off; int ly = li / S, lx = li % S;
  float acc = 0.f;
  for (int dy = -1; dy <= 1; ++dy) {
    int ny = ly + dy; if (ny < 0 || ny >= S) continue;
    for (int dx = -1; dx <= 1; ++dx) {
      int nx = lx + dx; if (nx < 0 || nx >= S) continue;
      acc += ssq[(size_t)b * L_TOT + off + ny * S + nx];
    }
  }
  float nrm = sqrtf(acc); nrm = fmaxf(nrm, 1e-4f);
  invn[idx] = 1.f / nrm;
}

// ---------------- K4c: per-pixel channel ssq of match_base (query side) ----------------
__global__ void k_ssqA(const float* __restrict__ mbb, float* __restrict__ ssqA, int n) {
  int idx = blockIdx.x * 256 + threadIdx.x;
  if (idx >= n) return;                      // n = 2*NPIX
  int p = idx % NPIX; int b = idx / NPIX;
  float s = 0.f;
  for (int c = 0; c < 32; ++c) { float v = mbb[(size_t)(b * 32 + c) * NPIX + p]; s += v * v; }
  ssqA[idx] = s;
}

// ---------------- K4d: 3x3 window (zero-pad) -> static log2-domain row max ----------------
// Mlog = 14.4269504 * max(0.7*||q||, ||q||-7): safe static softmax shift.
__global__ void k_m10(const float* __restrict__ ssqA, float* __restrict__ Mlog, int n) {
  int idx = blockIdx.x * 256 + threadIdx.x;
  if (idx >= n) return;                      // n = 2*NPIX
  int p = idx % NPIX; int b = idx / NPIX;
  int y = p / 64, x = p % 64;
  float acc = 0.f;
  for (int dy = -1; dy <= 1; ++dy) {
    int ny = y + dy; if (ny < 0 || ny >= 64) continue;
    for (int dx = -1; dx <= 1; ++dx) {
      int nx = x + dx; if (nx < 0 || nx >= 64) continue;
      acc += ssqA[(size_t)b * NPIX + ny * 64 + nx];
    }
  }
  float qn = sqrtf(acc);
  float m = fmaxf(0.7f * qn, qn - 7.f);
  Mlog[idx] = LOG2E10 * m;
}

// ---------------- K5: B im2col (normalized key patches) bf16 [b][l][288], zero tail ----------------
__global__ void k_bim(const float* __restrict__ mref, const float* __restrict__ invn,
                      ushort_t* __restrict__ Bm, int n) {
  int idx = blockIdx.x * 256 + threadIdx.x;
  if (idx >= n) return;                      // n = 2*L_PADB*288
  int k = idx % 288; int l = (idx / 288) % L_PADB; int b = idx / (288 * L_PADB);
  float v = 0.f;
  if (l < L_TOT) {
    int c = k / 9; int r = k % 9; int dy = r / 3 - 1, dx = r % 3 - 1;
    int S, off; decode_l(l, S, off);
    int li = l - off; int ly = li / S, lx = li % S;
    int ny = ly + dy, nx = lx + dx;
    if (ny >= 0 && ny < S && nx >= 0 && nx < S)
      v = mref[(size_t)(b * 32 + c) * L_TOT + off + ny * S + nx] * invn[(size_t)b * L_TOT + l];
  }
  Bm[(size_t)(b * L_PADB + l) * 288 + k] = f2bf(v);
}

// ---------------- K6: A im2col (query patches) bf16 [b][p][288] ----------------
__global__ void k_aim(const float* __restrict__ mbb, ushort_t* __restrict__ Am, int n) {
  int idx = blockIdx.x * 256 + threadIdx.x;
  if (idx >= n) return;                      // n = 2*NPIX*288
  int k = idx % 288; int p = (idx / 288) % NPIX; int b = idx / (288 * NPIX);
  int c = k / 9; int r = k % 9; int dy = r / 3 - 1, dx = r % 3 - 1;
  int y = p / 64, x = p % 64;
  int ny = y + dy, nx = x + dx;
  float v = 0.f;
  if (ny >= 0 && ny < 64 && nx >= 0 && nx < 64)
    v = mbb[(size_t)(b * 32 + c) * NPIX + ny * 64 + nx];
  Am[(size_t)(b * NPIX + p) * 288 + k] = f2bf(v);
}

// ---------------- K7: R value patches -> pre-swizzled chunk blocks ----------------
// Rs[b][ch]: slot = col*32 + (seg ^ ((col>>1)&3))*8 + (l&7), seg=(l_local>>3).
__global__ void k_rs(const float* __restrict__ aref, ushort_t* __restrict__ Rs, int n) {
  int idx = blockIdx.x * 256 + threadIdx.x;
  if (idx >= n) return;                      // n = 2*417*576*32
  int e = idx & 7; int phys = (idx >> 3) & 3; int col = (idx >> 5) % 576;
  int ch = (idx >> 5) / 576 % NCHT; int b = idx / (32 * 576 * NCHT);
  int seg = phys ^ ((col >> 1) & 3);
  int l = ch * 32 + seg * 8 + e;
  float v = 0.f;
  if (l < L_TOT) {
    int c = col / 9; int r = col % 9; int dy = r / 3 - 1, dx = r % 3 - 1;
    int S, off; decode_l(l, S, off);
    int li = l - off; int ly = li / S, lx = li % S;
    int ny = ly + dy, nx = lx + dx;
    if (ny >= 0 && ny < S && nx >= 0 && nx < S)
      v = aref[(size_t)(b * 64 + c) * L_TOT + off + ny * S + nx];
  }
  Rs[idx] = f2bf(v);
}

// ---------------- K8: static-max flash attention (R5 structure) ----------------
// grid 512: blockIdx -> tile(7b) | spl(1b) | b(1b). 256 thr = 4 waves.
// S: wave(rb,cbh) = 16 rows x 16 cols (B direct-reg, one-chunk prefetch).
// Z: wave owns 144 cols, all 32 rows; R from LDS dbuf (consumed after barrier).
__global__ __launch_bounds__(256, 2) void k_attn(const ushort_t* __restrict__ Am,
                                                 const ushort_t* __restrict__ Bm,
                                                 const ushort_t* __restrict__ Rs,
                                                 const float* __restrict__ Mlog,
                                                 float* __restrict__ Og,
                                                 float* __restrict__ Ol) {
  __shared__ ushort_t Rlds[2][RCHUNK_E];   // 73728 B dbuf R chunk (wave-private slabs)
  __shared__ ushort_t Plds[2][1024];       // 4 KB dbuf P tile (swizzled)
  int tid = threadIdx.x;
  int tile = blockIdx.x & 127; int spl = (blockIdx.x >> 7) & 1; int b = blockIdx.x >> 8;
  int p0 = tile * 32;
  int wave = tid >> 6, lane = tid & 63, quad = lane >> 4, ln = lane & 15;
  int rb = wave & 1, cbh = wave >> 1;
  int c0 = spl ? 209 : 0, c1 = spl ? NCHT : 209;

  bf16x8 af[9];
  {
    const ushort_t* arow = Am + (size_t)(b * NPIX + p0 + rb * 16 + ln) * 288;
    #pragma unroll
    for (int kk = 0; kk < 9; ++kk) af[kk] = *(const bf16x8*)(arow + kk * 32 + quad * 8);
  }
  float mlg[4];
  #pragma unroll
  for (int r = 0; r < 4; ++r)
    mlg[r] = Mlog[(size_t)b * NPIX + p0 + rb * 16 + quad * 4 + r];

  f32x4 acc[2][9];
  #pragma unroll
  for (int h = 0; h < 2; ++h)
    #pragma unroll
    for (int t = 0; t < 9; ++t) { acc[h][t][0] = acc[h][t][1] = acc[h][t][2] = acc[h][t][3] = 0.f; }
  float psum[4] = {0.f, 0.f, 0.f, 0.f};

  const ushort_t* RsB = Rs + (size_t)b * NCHT * RCHUNK_E + (size_t)(wave * 9) * 512 + lane * 8;
  const ushort_t* BmB = Bm + (size_t)b * L_PADB * 288 + quad * 8;

  // prologue: stage R chunk c0 (first read is after the first in-loop barrier), B frags c0
  {
    const ushort_t* src = RsB + (size_t)c0 * RCHUNK_E;
    ushort_t* dst = &Rlds[c0 & 1][wave * 9 * 512];
    #pragma unroll
    for (int i = 0; i < 9; ++i) gll16(src + i * 512, dst + i * 512);
  }
  bf16x8 bcur[9];
  {
    int col = c0 * 32 + cbh * 16 + ln;
    const ushort_t* brow = BmB + (size_t)col * 288;
    #pragma unroll
    for (int kk = 0; kk < 9; ++kk) bcur[kk] = *(const bf16x8*)(brow + kk * 32);
  }

  for (int ch = c0; ch < c1; ++ch) {
    int par = ch & 1;
    int cp = ch + 1 < NCHT ? ch + 1 : NCHT - 1;
    // stage next R chunk into other buffer (wave-private slab)
    {
      const ushort_t* src = RsB + (size_t)cp * RCHUNK_E;
      ushort_t* dst = &Rlds[par ^ 1][wave * 9 * 512];
      #pragma unroll
      for (int i = 0; i < 9; ++i) gll16(src + i * 512, dst + i * 512);
    }
    // S-MFMA: two independent accumulator chains
    f32x4 sa, sb;
    sa[0] = sa[1] = sa[2] = sa[3] = 0.f;
    sb[0] = sb[1] = sb[2] = sb[3] = 0.f;
    #pragma unroll
    for (int kk = 0; kk < 4; ++kk)
      sa = __builtin_amdgcn_mfma_f32_16x16x32_bf16(af[kk], bcur[kk], sa, 0, 0, 0);
    #pragma unroll
    for (int kk = 4; kk < 8; ++kk)
      sb = __builtin_amdgcn_mfma_f32_16x16x32_bf16(af[kk], bcur[kk], sb, 0, 0, 0);
    sa = __builtin_amdgcn_mfma_f32_16x16x32_bf16(af[8], bcur[8], sa, 0, 0, 0);
    // prefetch next B frags
    bf16x8 bnext[9];
    {
      int coln = cp * 32 + cbh * 16 + ln;
      const ushort_t* brow = BmB + (size_t)coln * 288;
      #pragma unroll
      for (int kk = 0; kk < 9; ++kk) bnext[kk] = *(const bf16x8*)(brow + kk * 32);
    }
    // P = 2^(14.43*s - Mlog); write swizzled dbuf P; accumulate deferred row-sum
    int colw = ch * 32 + cbh * 16 + ln;
    bool valid = colw < L_TOT;
    #pragma unroll
    for (int r = 0; r < 4; ++r) {
      float sv = sa[r] + sb[r];
      float pv = valid ? exp2f(fmaf(sv, LOG2E10, -mlg[r])) : 0.f;
      int row = rb * 16 + quad * 4 + r;
      int seg = cbh * 2 + (ln >> 3);
      int swz = seg ^ ((row >> 1) & 3);
      Plds[par][row * 32 + swz * 8 + (ln & 7)] = f2bf(pv);
      psum[r] += pv;
    }
    __syncthreads();   // P ready + R DMA drained (only barrier per chunk)
    // Z-GEMM: P(32x32) @ R(32 x 144-per-wave) from LDS
    bf16x8 pf0, pf1;
    {
      int sw0 = quad ^ ((ln >> 1) & 3);
      int sw1 = quad ^ (((16 + ln) >> 1) & 3);
      pf0 = *(const bf16x8*)&Plds[par][ln * 32 + sw0 * 8];
      pf1 = *(const bf16x8*)&Plds[par][(16 + ln) * 32 + sw1 * 8];
    }
    #pragma unroll
    for (int t = 0; t < 9; ++t) {
      int col = wave * 144 + t * 16 + ln;
      int swz = quad ^ ((col >> 1) & 3);
      bf16x8 rf = *(const bf16x8*)&Rlds[par][col * 32 + swz * 8];
      acc[0][t] = __builtin_amdgcn_mfma_f32_16x16x32_bf16(pf0, rf, acc[0][t], 0, 0, 0);
      acc[1][t] = __builtin_amdgcn_mfma_f32_16x16x32_bf16(pf1, rf, acc[1][t], 0, 0, 0);
    }
    #pragma unroll
    for (int kk = 0; kk < 9; ++kk) bcur[kk] = bnext[kk];
  }

  // epilogue: reduce deferred row-sums over the 16 lanes of each quad
  #pragma unroll
  for (int m = 1; m <= 8; m <<= 1)
    #pragma unroll
    for (int r = 0; r < 4; ++r) psum[r] += __shfl_xor(psum[r], m);
  int sb2 = spl * 2 + b;
  if (ln == 0) {
    #pragma unroll
    for (int r = 0; r < 4; ++r) {
      int row = p0 + rb * 16 + quad * 4 + r;
      Ol[(size_t)(sb2 * 2 + cbh) * NPIX + row] = psum[r];
    }
  }
  #pragma unroll
  for (int h = 0; h < 2; ++h)
    #pragma unroll
    for (int t = 0; t < 9; ++t) {
      int colg = wave * 144 + t * 16 + ln;
      #pragma unroll
      for (int r = 0; r < 4; ++r) {
        int row = p0 + h * 16 + quad * 4 + r;
        Og[((size_t)sb2 * NPIX + row) * 576 + colg] = acc[h][t][r];
      }
    }
}

// ---------------- K9: inv = 1 / sum of 4 partial row-sums ----------------
__global__ void k_inv(const float* __restrict__ Ol, float* __restrict__ inv, int n) {
  int idx = blockIdx.x * 256 + threadIdx.x;
  if (idx >= n) return;                      // n = 2*NPIX; idx = b*NPIX+p
  int b = idx / NPIX; int p = idx % NPIX;
  float s = 0.f;
  #pragma unroll
  for (int spl = 0; spl < 2; ++spl)
    #pragma unroll
    for (int cbh = 0; cbh < 2; ++cbh)
      s += Ol[(size_t)(((spl * 2 + b) * 2) + cbh) * NPIX + p];
  inv[idx] = 1.f / s;
}

// ---------------- K10: 9-tap gather, c-fastest lanes + LDS transpose ----------------
// grid 128 = b(2) x y(64); 256 threads. Tap reads: lanes consecutive in c ->
// 36 B lane stride (vs 2304 B) and the 27 taps of one pixel share line windows.
__global__ void k_final(const float* __restrict__ Og, const float* __restrict__ inv,
                        const float* __restrict__ input, float* __restrict__ out) {
  __shared__ float T[64][65];
  int y = blockIdx.x & 63; int b = blockIdx.x >> 6;
  int tid = threadIdx.x;
  const size_t S1 = (size_t)2 * NPIX * 576;
  for (int it = 0; it < 16; ++it) {
    int lin = it * 256 + tid;
    int c = lin & 63, x = lin >> 6;
    float acc = 0.f;
    for (int j = 0; j < 3; ++j) {
      int qy = y + 1 - j; if (qy < 0 || qy >= 64) continue;
      for (int i2 = 0; i2 < 3; ++i2) {
        int qx = x + 1 - i2; if (qx < 0 || qx >= 64) continue;
        int p = qy * 64 + qx;
        size_t e = ((size_t)b * NPIX + p) * 576 + c * 9 + j * 3 + i2;
        acc += (Og[e] + Og[e + S1]) * inv[b * NPIX + p];
      }
    }
    T[x][c] = acc;
  }
  __syncthreads();
  for (int it = 0; it < 16; ++it) {
    int lin = it * 256 + tid;
    int x = lin & 63, c = lin >> 6;
    int o = ((b * 64 + c) * 64 + y) * 64 + x;   // lanes consecutive x -> coalesced
    out[o] = 0.25f * T[x][c] + input[o];
  }
}

extern "C" void kernel_launch(void* const* d_in, const int* in_sizes, int n_in,
                              void* d_out, int out_size, void* d_ws, size_t ws_size,
                              hipStream_t stream) {
  (void)in_sizes; (void)n_in; (void)out_size; (void)ws_size;
  const float* input = (const float*)d_in[0];
  const float* inref = (const float*)d_in[1];
  const float* Wb = (const float*)d_in[2];
  const float* bb = (const float*)d_in[3];
  const float* Wm = (const float*)d_in[4];
  const float* bm = (const float*)d_in[5];
  const float* Wa = (const float*)d_in[6];
  const float* ba = (const float*)d_in[7];
  const float* ap = (const float*)d_in[8];
  float* out = (float*)d_out;

  char* ws = (char*)d_ws;
  size_t off = 0;
  auto alloc = [&](size_t bytes) -> char* {
    char* p = ws + off; off = (off + bytes + 255) & ~(size_t)255; return p;
  };
  // persistent region
  ushort_t* Am   = (ushort_t*)alloc((size_t)2 * NPIX * 288 * 2);        // 4.7 MB
  ushort_t* Bm   = (ushort_t*)alloc((size_t)2 * L_PADB * 288 * 2);      // 15.4 MB
  ushort_t* Rs   = (ushort_t*)alloc((size_t)2 * NCHT * RCHUNK_E * 2);   // 30.7 MB
  float*    Ol   = (float*)alloc((size_t)8 * NPIX * 4);
  float*    inv  = (float*)alloc((size_t)2 * NPIX * 4);
  float*    Mlog = (float*)alloc((size_t)2 * NPIX * 4);
  float*    ssqA = (float*)alloc((size_t)2 * NPIX * 4);
  // big region: Og (37.7 MB) aliases the early prep buffers (dead before k_attn)
  size_t og_bytes = (size_t)4 * NPIX * 576 * 4;
  char* big = alloc(og_bytes);
  float* Og = (float*)big;
  size_t eoff = 0;
  auto ealloc = [&](size_t bytes) -> char* {
    char* p = big + eoff; eoff = (eoff + bytes + 255) & ~(size_t)255; return p;
  };
  float* refbuf = (float*)ealloc((size_t)2 * 64 * L_TOT * 4);
  float* mref   = (float*)ealloc((size_t)2 * 32 * L_TOT * 4);
  float* aref   = (float*)ealloc((size_t)2 * 64 * L_TOT * 4);
  float* mbb    = (float*)ealloc((size_t)2 * 32 * NPIX * 4);
  float* ssq    = (float*)ealloc((size_t)2 * L_TOT * 4);
  float* invn   = (float*)ealloc((size_t)2 * L_TOT * 4);
  // total ws ~ 89 MB

  int n1 = 2 * 64 * L_TOT;
  k_resize<<<(n1 + 255) / 256, 256, 0, stream>>>(inref, refbuf, n1);
  k_convref<<<212, 256, 0, stream>>>(refbuf, Wm, bm, Wa, ba, ap, mref, aref);
  int n3 = 2 * 32 * NPIX;
  k_mb<<<(n3 + 255) / 256, 256, 0, stream>>>(input, Wb, bb, ap, mbb, n3);
  int n4 = 2 * L_TOT;
  k_ssq<<<(n4 + 255) / 256, 256, 0, stream>>>(mref, ssq, n4);
  k_invn<<<(n4 + 255) / 256, 256, 0, stream>>>(ssq, invn, n4);
  int n4a = 2 * NPIX;
  k_ssqA<<<(n4a + 255) / 256, 256, 0, stream>>>(mbb, ssqA, n4a);
  k_m10<<<(n4a + 255) / 256, 256, 0, stream>>>(ssqA, Mlog, n4a);
  int n5 = 2 * L_PADB * 288;
  k_bim<<<(n5 + 255) / 256, 256, 0, stream>>>(mref, invn, Bm, n5);
  int n6 = 2 * NPIX * 288;
  k_aim<<<(n6 + 255) / 256, 256, 0, stream>>>(mbb, Am, n6);
  int n7 = 2 * NCHT * 576 * 32;
  k_rs<<<(n7 + 255) / 256, 256, 0, stream>>>(aref, Rs, n7);

  k_attn<<<512, 256, 0, stream>>>(Am, Bm, Rs, Mlog, Og, Ol);
  k_inv<<<(2 * NPIX + 255) / 256, 256, 0, stream>>>(Ol, inv, 2 * NPIX);
  k_final<<<128, 256, 0, stream>>>(Og, inv, input, out);
}

// Round 10
// 660.511 us; speedup vs baseline: 1.3208x; 1.0479x over previous
//
#include <hip/hip_runtime.h>
#include <stdint.h>

// PyramidAttention gfx950 — round 10: k_attn untouched (R5/R9 proven structure);
// prep tail optimized: k_final on 256 blocks (full CU coverage), k_rs/k_bim/k_aim
// vectorized x8 (one uint4 store per thread instead of 8 scalar 2B stores).

typedef __attribute__((ext_vector_type(8))) short bf16x8;
typedef __attribute__((ext_vector_type(4))) float f32x4;
typedef unsigned short ushort_t;

#define L_TOT  13326
#define L_PADB 13344   // 417 chunks * 32
#define NCHT   417
#define NPIX   4096
#define RCHUNK_E 18432 // 576 cols * 32 l
#define LOG2E10 14.4269504f   // 10*log2(e)
#define CT 256         // k_convref l-tile

__device__ __forceinline__ float cubw(float d) {
  d = fabsf(d);
  if (d <= 1.f) return (1.25f * d - 2.25f) * d * d + 1.f;          // A=-0.75
  if (d < 2.f)  return ((-0.75f * d + 3.75f) * d - 6.f) * d + 3.f;
  return 0.f;
}

__device__ __forceinline__ void decode_l(int l, int& S, int& off) {
  if (l < 4096)       { S = 64; off = 0; }
  else if (l < 7345)  { S = 57; off = 4096; }
  else if (l < 9946)  { S = 51; off = 7345; }
  else if (l < 11882) { S = 44; off = 9946; }
  else                { S = 38; off = 11882; }
}

__device__ __forceinline__ ushort_t f2bf(float f) {
  union { float f; uint32_t u; } v; v.f = f;
  uint32_t r = (v.u + 0x7fffu + ((v.u >> 16) & 1u)) >> 16;  // RNE
  return (ushort_t)r;
}

__device__ __forceinline__ float preluf(float x, float a) { return x >= 0.f ? x : a * x; }

__device__ __forceinline__ void gll16(const ushort_t* g, ushort_t* l) {
  __builtin_amdgcn_global_load_lds(
      (const __attribute__((address_space(1))) unsigned int*)g,
      (__attribute__((address_space(3))) unsigned int*)l, 16, 0, 0);
}

// ---------------- K1: bicubic resize (align_corners=True, border clamp) ----------------
__global__ void k_resize(const float* __restrict__ inref, float* __restrict__ refbuf, int n) {
  int idx = blockIdx.x * 256 + threadIdx.x;
  if (idx >= n) return;                      // n = 2*64*L_TOT, idx -> (b*64+c, l)
  int l = idx % L_TOT; int bc = idx / L_TOT;
  int S, off; decode_l(l, S, off);
  int li = l - off; int ly = li / S, lx = li % S;
  float val;
  if (S == 64) {
    val = inref[(size_t)bc * 4096 + ly * 64 + lx];
  } else {
    float sc = (float)(63.0 / (double)(S - 1));
    float sy = (float)ly * sc, sx = (float)lx * sc;
    int iy = (int)floorf(sy), ix = (int)floorf(sx);
    float fy = sy - (float)iy, fx = sx - (float)ix;
    float wy[4] = { cubw(fy + 1.f), cubw(fy), cubw(1.f - fy), cubw(2.f - fy) };
    float wx[4] = { cubw(fx + 1.f), cubw(fx), cubw(1.f - fx), cubw(2.f - fx) };
    val = 0.f;
    for (int t = 0; t < 4; ++t) {
      int ty = iy - 1 + t; ty = ty < 0 ? 0 : (ty > 63 ? 63 : ty);
      float rv = 0.f;
      for (int u = 0; u < 4; ++u) {
        int tx = ix - 1 + u; tx = tx < 0 ? 0 : (tx > 63 ? 63 : tx);
        rv += wx[u] * inref[(size_t)bc * 4096 + ty * 64 + tx];
      }
      val += wy[t] * rv;
    }
  }
  refbuf[(size_t)bc * L_TOT + l] = val;
}

// ---------------- K2: conv1x1 + prelu, LDS-tiled (refbuf read ONCE) ----------------
__global__ void k_convref(const float* __restrict__ refbuf,
                          const float* __restrict__ Wm, const float* __restrict__ bm,
                          const float* __restrict__ Wa, const float* __restrict__ ba,
                          const float* __restrict__ ap,
                          float* __restrict__ mref, float* __restrict__ aref) {
  __shared__ float T[64][CT];   // 64 KB tile: 64 in-ch x 256 l
  int blk = blockIdx.x;
  int oh = blk & 1; int lt = (blk >> 1) % 53; int b = blk / 106;
  int l0 = lt * CT;
  int tid = threadIdx.x;
  float a = ap[0];
  for (int i = tid; i < 64 * CT; i += 256) {
    int c = i >> 8; int l = i & 255;
    int gl = l0 + l;
    T[c][l] = (gl < L_TOT) ? refbuf[(size_t)(b * 64 + c) * L_TOT + gl] : 0.f;
  }
  __syncthreads();
  int gl = l0 + tid;
  if (gl >= L_TOT) return;
  for (int oc = oh * 48; oc < oh * 48 + 48; ++oc) {
    const float* Wrow; float s;
    if (oc < 32) { Wrow = Wm + oc * 64; s = bm[oc]; }
    else         { Wrow = Wa + (oc - 32) * 64; s = ba[oc - 32]; }
    #pragma unroll 8
    for (int c = 0; c < 64; ++c) s += Wrow[c] * T[c][tid];
    s = preluf(s, a);
    if (oc < 32) mref[(size_t)(b * 32 + oc) * L_TOT + gl] = s;
    else         aref[(size_t)(b * 64 + oc - 32) * L_TOT + gl] = s;
  }
}

// ---------------- K3: match_base = prelu(Wb@input+bb) ----------------
__global__ void k_mb(const float* __restrict__ input, const float* __restrict__ Wb,
                     const float* __restrict__ bb, const float* __restrict__ ap,
                     float* __restrict__ mbb, int n) {
  int idx = blockIdx.x * 256 + threadIdx.x;
  if (idx >= n) return;                      // n = 2*32*NPIX
  int p = idx % NPIX; int cm = (idx / NPIX) % 32; int b = idx / (32 * NPIX);
  float a = ap[0];
  float acc = bb[cm];
  for (int c = 0; c < 64; ++c) acc += Wb[cm * 64 + c] * input[(size_t)(b * 64 + c) * NPIX + p];
  mbb[(size_t)(b * 32 + cm) * NPIX + p] = preluf(acc, a);
}

// ---------------- K4a: per-position sum of squares of mref (key side) ----------------
__global__ void k_ssq(const float* __restrict__ mref, float* __restrict__ ssq, int n) {
  int idx = blockIdx.x * 256 + threadIdx.x;
  if (idx >= n) return;                      // n = 2*L_TOT
  int l = idx % L_TOT; int b = idx / L_TOT;
  float s = 0.f;
  for (int c = 0; c < 32; ++c) { float v = mref[(size_t)(b * 32 + c) * L_TOT + l]; s += v * v; }
  ssq[idx] = s;
}

// ---------------- K4b: 3x3 window sum -> 1/max(sqrt, 1e-4) (key norm) ----------------
__global__ void k_invn(const float* __restrict__ ssq, float* __restrict__ invn, int n) {
  int idx = blockIdx.x * 256 + threadIdx.x;
  if (idx >= n) return;
  int l = idx % L_TOT; int b = idx / L_TOT;
  int S, off; decode_l(l, S, off);
  int li = l - off; int ly = li / S, lx = li % S;
  float acc = 0.f;
  for (int dy = -1; dy <= 1; ++dy) {
    int ny = ly + dy; if (ny < 0 || ny >= S) continue;
    for (int dx = -1; dx <= 1; ++dx) {
      int nx = lx + dx; if (nx < 0 || nx >= S) continue;
      acc += ssq[(size_t)b * L_TOT + off + ny * S + nx];
    }
  }
  float nrm = sqrtf(acc); nrm = fmaxf(nrm, 1e-4f);
  invn[idx] = 1.f / nrm;
}

// ---------------- K4c: per-pixel channel ssq of match_base (query side) ----------------
__global__ void k_ssqA(const float* __restrict__ mbb, float* __restrict__ ssqA, int n) {
  int idx = blockIdx.x * 256 + threadIdx.x;
  if (idx >= n) return;                      // n = 2*NPIX
  int p = idx % NPIX; int b = idx / NPIX;
  float s = 0.f;
  for (int c = 0; c < 32; ++c) { float v = mbb[(size_t)(b * 32 + c) * NPIX + p]; s += v * v; }
  ssqA[idx] = s;
}

// ---------------- K4d: 3x3 window (zero-pad) -> static log2-domain row max ----------------
__global__ void k_m10(const float* __restrict__ ssqA, float* __restrict__ Mlog, int n) {
  int idx = blockIdx.x * 256 + threadIdx.x;
  if (idx >= n) return;                      // n = 2*NPIX
  int p = idx % NPIX; int b = idx / NPIX;
  int y = p / 64, x = p % 64;
  float acc = 0.f;
  for (int dy = -1; dy <= 1; ++dy) {
    int ny = y + dy; if (ny < 0 || ny >= 64) continue;
    for (int dx = -1; dx <= 1; ++dx) {
      int nx = x + dx; if (nx < 0 || nx >= 64) continue;
      acc += ssqA[(size_t)b * NPIX + ny * 64 + nx];
    }
  }
  float qn = sqrtf(acc);
  float m = fmaxf(0.7f * qn, qn - 7.f);
  Mlog[idx] = LOG2E10 * m;
}

// ---------------- K5: B im2col bf16 [b][l][288], vec8 (one uint4 store/thread) ----------------
__global__ void k_bim(const float* __restrict__ mref, const float* __restrict__ invn,
                      ushort_t* __restrict__ Bm, int n) {
  int idx = blockIdx.x * 256 + threadIdx.x;
  if (idx >= n) return;                      // n = 2*L_PADB*36
  int k8 = idx % 36; int l = (idx / 36) % L_PADB; int b = idx / (36 * L_PADB);
  ushort_t v[8];
  if (l < L_TOT) {
    int S, off; decode_l(l, S, off);
    int li = l - off; int ly = li / S, lx = li % S;
    float iv = invn[(size_t)b * L_TOT + l];
    #pragma unroll
    for (int e = 0; e < 8; ++e) {
      int k = k8 * 8 + e;
      int c = k / 9; int r = k % 9; int dy = r / 3 - 1, dx = r % 3 - 1;
      int ny = ly + dy, nx = lx + dx;
      float val = 0.f;
      if (ny >= 0 && ny < S && nx >= 0 && nx < S)
        val = mref[(size_t)(b * 32 + c) * L_TOT + off + ny * S + nx] * iv;
      v[e] = f2bf(val);
    }
  } else {
    #pragma unroll
    for (int e = 0; e < 8; ++e) v[e] = 0;
  }
  *(uint4*)(Bm + ((size_t)(b * L_PADB + l) * 288 + k8 * 8)) = *(const uint4*)v;
}

// ---------------- K6: A im2col bf16 [b][p][288], vec8 ----------------
__global__ void k_aim(const float* __restrict__ mbb, ushort_t* __restrict__ Am, int n) {
  int idx = blockIdx.x * 256 + threadIdx.x;
  if (idx >= n) return;                      // n = 2*NPIX*36
  int k8 = idx % 36; int p = (idx / 36) % NPIX; int b = idx / (36 * NPIX);
  int y = p / 64, x = p % 64;
  ushort_t v[8];
  #pragma unroll
  for (int e = 0; e < 8; ++e) {
    int k = k8 * 8 + e;
    int c = k / 9; int r = k % 9; int dy = r / 3 - 1, dx = r % 3 - 1;
    int ny = y + dy, nx = x + dx;
    float val = 0.f;
    if (ny >= 0 && ny < 64 && nx >= 0 && nx < 64)
      val = mbb[(size_t)(b * 32 + c) * NPIX + ny * 64 + nx];
    v[e] = f2bf(val);
  }
  *(uint4*)(Am + ((size_t)(b * NPIX + p) * 288 + k8 * 8)) = *(const uint4*)v;
}

// ---------------- K7: R value patches -> pre-swizzled chunk blocks, vec8 ----------------
// slot = col*32 + phys*8 + e holds l = ch*32 + (phys^((col>>1)&3))*8 + e.
__global__ void k_rs(const float* __restrict__ aref, ushort_t* __restrict__ Rs, int n) {
  int idx = blockIdx.x * 256 + threadIdx.x;
  if (idx >= n) return;                      // n = 2*NCHT*576*4
  int phys = idx & 3; int q = idx >> 2;
  int col = q % 576; q /= 576;
  int ch = q % NCHT; int b = q / NCHT;
  int c = col / 9; int r = col % 9; int dy = r / 3 - 1, dx = r % 3 - 1;
  int seg = phys ^ ((col >> 1) & 3);
  int lbase = ch * 32 + seg * 8;
  ushort_t v[8];
  #pragma unroll
  for (int e = 0; e < 8; ++e) {
    int l = lbase + e;
    float val = 0.f;
    if (l < L_TOT) {
      int S, off; decode_l(l, S, off);
      int li = l - off; int ly = li / S, lx = li % S;
      int ny = ly + dy, nx = lx + dx;
      if (ny >= 0 && ny < S && nx >= 0 && nx < S)
        val = aref[(size_t)(b * 64 + c) * L_TOT + off + ny * S + nx];
    }
    v[e] = f2bf(val);
  }
  *(uint4*)(Rs + ((size_t)(b * NCHT + ch) * RCHUNK_E + col * 32 + phys * 8)) = *(const uint4*)v;
}

// ---------------- K8: static-max flash attention (R5/R9 proven structure) ----------------
// grid 512: blockIdx -> tile(7b) | spl(1b) | b(1b). 256 thr = 4 waves.
// S: wave(rb,cbh) = 16 rows x 16 cols (B direct-reg, one-chunk prefetch).
// Z: wave owns 144 cols, all 32 rows; R from LDS dbuf (consumed after barrier).
__global__ __launch_bounds__(256, 2) void k_attn(const ushort_t* __restrict__ Am,
                                                 const ushort_t* __restrict__ Bm,
                                                 const ushort_t* __restrict__ Rs,
                                                 const float* __restrict__ Mlog,
                                                 float* __restrict__ Og,
                                                 float* __restrict__ Ol) {
  __shared__ ushort_t Rlds[2][RCHUNK_E];   // 73728 B dbuf R chunk (wave-private slabs)
  __shared__ ushort_t Plds[2][1024];       // 4 KB dbuf P tile (swizzled)
  int tid = threadIdx.x;
  int tile = blockIdx.x & 127; int spl = (blockIdx.x >> 7) & 1; int b = blockIdx.x >> 8;
  int p0 = tile * 32;
  int wave = tid >> 6, lane = tid & 63, quad = lane >> 4, ln = lane & 15;
  int rb = wave & 1, cbh = wave >> 1;
  int c0 = spl ? 209 : 0, c1 = spl ? NCHT : 209;

  bf16x8 af[9];
  {
    const ushort_t* arow = Am + (size_t)(b * NPIX + p0 + rb * 16 + ln) * 288;
    #pragma unroll
    for (int kk = 0; kk < 9; ++kk) af[kk] = *(const bf16x8*)(arow + kk * 32 + quad * 8);
  }
  float mlg[4];
  #pragma unroll
  for (int r = 0; r < 4; ++r)
    mlg[r] = Mlog[(size_t)b * NPIX + p0 + rb * 16 + quad * 4 + r];

  f32x4 acc[2][9];
  #pragma unroll
  for (int h = 0; h < 2; ++h)
    #pragma unroll
    for (int t = 0; t < 9; ++t) { acc[h][t][0] = acc[h][t][1] = acc[h][t][2] = acc[h][t][3] = 0.f; }
  float psum[4] = {0.f, 0.f, 0.f, 0.f};

  const ushort_t* RsB = Rs + (size_t)b * NCHT * RCHUNK_E + (size_t)(wave * 9) * 512 + lane * 8;
  const ushort_t* BmB = Bm + (size_t)b * L_PADB * 288 + quad * 8;

  // prologue: stage R chunk c0 (first read after first in-loop barrier), B frags c0
  {
    const ushort_t* src = RsB + (size_t)c0 * RCHUNK_E;
    ushort_t* dst = &Rlds[c0 & 1][wave * 9 * 512];
    #pragma unroll
    for (int i = 0; i < 9; ++i) gll16(src + i * 512, dst + i * 512);
  }
  bf16x8 bcur[9];
  {
    int col = c0 * 32 + cbh * 16 + ln;
    const ushort_t* brow = BmB + (size_t)col * 288;
    #pragma unroll
    for (int kk = 0; kk < 9; ++kk) bcur[kk] = *(const bf16x8*)(brow + kk * 32);
  }

  for (int ch = c0; ch < c1; ++ch) {
    int par = ch & 1;
    int cp = ch + 1 < NCHT ? ch + 1 : NCHT - 1;
    // stage next R chunk into other buffer (wave-private slab)
    {
      const ushort_t* src = RsB + (size_t)cp * RCHUNK_E;
      ushort_t* dst = &Rlds[par ^ 1][wave * 9 * 512];
      #pragma unroll
      for (int i = 0; i < 9; ++i) gll16(src + i * 512, dst + i * 512);
    }
    // S-MFMA: two independent accumulator chains
    f32x4 sa, sb;
    sa[0] = sa[1] = sa[2] = sa[3] = 0.f;
    sb[0] = sb[1] = sb[2] = sb[3] = 0.f;
    #pragma unroll
    for (int kk = 0; kk < 4; ++kk)
      sa = __builtin_amdgcn_mfma_f32_16x16x32_bf16(af[kk], bcur[kk], sa, 0, 0, 0);
    #pragma unroll
    for (int kk = 4; kk < 8; ++kk)
      sb = __builtin_amdgcn_mfma_f32_16x16x32_bf16(af[kk], bcur[kk], sb, 0, 0, 0);
    sa = __builtin_amdgcn_mfma_f32_16x16x32_bf16(af[8], bcur[8], sa, 0, 0, 0);
    // prefetch next B frags
    bf16x8 bnext[9];
    {
      int coln = cp * 32 + cbh * 16 + ln;
      const ushort_t* brow = BmB + (size_t)coln * 288;
      #pragma unroll
      for (int kk = 0; kk < 9; ++kk) bnext[kk] = *(const bf16x8*)(brow + kk * 32);
    }
    // P = 2^(14.43*s - Mlog); write swizzled dbuf P; accumulate deferred row-sum
    int colw = ch * 32 + cbh * 16 + ln;
    bool valid = colw < L_TOT;
    #pragma unroll
    for (int r = 0; r < 4; ++r) {
      float sv = sa[r] + sb[r];
      float pv = valid ? exp2f(fmaf(sv, LOG2E10, -mlg[r])) : 0.f;
      int row = rb * 16 + quad * 4 + r;
      int seg = cbh * 2 + (ln >> 3);
      int swz = seg ^ ((row >> 1) & 3);
      Plds[par][row * 32 + swz * 8 + (ln & 7)] = f2bf(pv);
      psum[r] += pv;
    }
    __syncthreads();   // P ready + R DMA drained (only barrier per chunk)
    // Z-GEMM: P(32x32) @ R(32 x 144-per-wave) from LDS
    bf16x8 pf0, pf1;
    {
      int sw0 = quad ^ ((ln >> 1) & 3);
      int sw1 = quad ^ (((16 + ln) >> 1) & 3);
      pf0 = *(const bf16x8*)&Plds[par][ln * 32 + sw0 * 8];
      pf1 = *(const bf16x8*)&Plds[par][(16 + ln) * 32 + sw1 * 8];
    }
    #pragma unroll
    for (int t = 0; t < 9; ++t) {
      int col = wave * 144 + t * 16 + ln;
      int swz = quad ^ ((col >> 1) & 3);
      bf16x8 rf = *(const bf16x8*)&Rlds[par][col * 32 + swz * 8];
      acc[0][t] = __builtin_amdgcn_mfma_f32_16x16x32_bf16(pf0, rf, acc[0][t], 0, 0, 0);
      acc[1][t] = __builtin_amdgcn_mfma_f32_16x16x32_bf16(pf1, rf, acc[1][t], 0, 0, 0);
    }
    #pragma unroll
    for (int kk = 0; kk < 9; ++kk) bcur[kk] = bnext[kk];
  }

  // epilogue: reduce deferred row-sums over the 16 lanes of each quad
  #pragma unroll
  for (int m = 1; m <= 8; m <<= 1)
    #pragma unroll
    for (int r = 0; r < 4; ++r) psum[r] += __shfl_xor(psum[r], m);
  int sb2 = spl * 2 + b;
  if (ln == 0) {
    #pragma unroll
    for (int r = 0; r < 4; ++r) {
      int row = p0 + rb * 16 + quad * 4 + r;
      Ol[(size_t)(sb2 * 2 + cbh) * NPIX + row] = psum[r];
    }
  }
  #pragma unroll
  for (int h = 0; h < 2; ++h)
    #pragma unroll
    for (int t = 0; t < 9; ++t) {
      int colg = wave * 144 + t * 16 + ln;
      #pragma unroll
      for (int r = 0; r < 4; ++r) {
        int row = p0 + h * 16 + quad * 4 + r;
        Og[((size_t)sb2 * NPIX + row) * 576 + colg] = acc[h][t][r];
      }
    }
}

// ---------------- K9: inv = 1 / sum of 4 partial row-sums ----------------
__global__ void k_inv(const float* __restrict__ Ol, float* __restrict__ inv, int n) {
  int idx = blockIdx.x * 256 + threadIdx.x;
  if (idx >= n) return;                      // n = 2*NPIX; idx = b*NPIX+p
  int b = idx / NPIX; int p = idx % NPIX;
  float s = 0.f;
  #pragma unroll
  for (int spl = 0; spl < 2; ++spl)
    #pragma unroll
    for (int cbh = 0; cbh < 2; ++cbh)
      s += Ol[(size_t)(((spl * 2 + b) * 2) + cbh) * NPIX + p];
  inv[idx] = 1.f / s;
}

// ---------------- K10: 9-tap gather, c-fastest lanes + LDS transpose, 256 blocks ----------------
// grid 256 = xh(1b) | y(6b) | b(1b); 256 threads; each block does 32 x * 64 c.
__global__ void k_final(const float* __restrict__ Og, const float* __restrict__ inv,
                        const float* __restrict__ input, float* __restrict__ out) {
  __shared__ float T[32][65];
  int blk = blockIdx.x;
  int xh = blk & 1; int y = (blk >> 1) & 63; int b = blk >> 7;
  int tid = threadIdx.x;
  const size_t S1 = (size_t)2 * NPIX * 576;
  for (int it = 0; it < 8; ++it) {
    int lin = it * 256 + tid;
    int c = lin & 63, x32 = lin >> 6;
    int x = xh * 32 + x32;
    float acc = 0.f;
    for (int j = 0; j < 3; ++j) {
      int qy = y + 1 - j; if (qy < 0 || qy >= 64) continue;
      for (int i2 = 0; i2 < 3; ++i2) {
        int qx = x + 1 - i2; if (qx < 0 || qx >= 64) continue;
        int p = qy * 64 + qx;
        size_t e = ((size_t)b * NPIX + p) * 576 + c * 9 + j * 3 + i2;
        acc += (Og[e] + Og[e + S1]) * inv[b * NPIX + p];
      }
    }
    T[x32][c] = acc;
  }
  __syncthreads();
  for (int it = 0; it < 8; ++it) {
    int lin = it * 256 + tid;
    int x32 = lin & 31, c = lin >> 5;
    int o = ((b * 64 + c) * 64 + y) * 64 + xh * 32 + x32;   // lanes consecutive x
    out[o] = 0.25f * T[x32][c] + input[o];
  }
}

extern "C" void kernel_launch(void* const* d_in, const int* in_sizes, int n_in,
                              void* d_out, int out_size, void* d_ws, size_t ws_size,
                              hipStream_t stream) {
  (void)in_sizes; (void)n_in; (void)out_size; (void)ws_size;
  const float* input = (const float*)d_in[0];
  const float* inref = (const float*)d_in[1];
  const float* Wb = (const float*)d_in[2];
  const float* bb = (const float*)d_in[3];
  const float* Wm = (const float*)d_in[4];
  const float* bm = (const float*)d_in[5];
  const float* Wa = (const float*)d_in[6];
  const float* ba = (const float*)d_in[7];
  const float* ap = (const float*)d_in[8];
  float* out = (float*)d_out;

  char* ws = (char*)d_ws;
  size_t off = 0;
  auto alloc = [&](size_t bytes) -> char* {
    char* p = ws + off; off = (off + bytes + 255) & ~(size_t)255; return p;
  };
  // persistent region
  ushort_t* Am   = (ushort_t*)alloc((size_t)2 * NPIX * 288 * 2);        // 4.7 MB
  ushort_t* Bm   = (ushort_t*)alloc((size_t)2 * L_PADB * 288 * 2);      // 15.4 MB
  ushort_t* Rs   = (ushort_t*)alloc((size_t)2 * NCHT * RCHUNK_E * 2);   // 30.7 MB
  float*    Ol   = (float*)alloc((size_t)8 * NPIX * 4);
  float*    inv  = (float*)alloc((size_t)2 * NPIX * 4);
  float*    Mlog = (float*)alloc((size_t)2 * NPIX * 4);
  float*    ssqA = (float*)alloc((size_t)2 * NPIX * 4);
  // big region: Og (37.7 MB) aliases the early prep buffers (dead before k_attn)
  size_t og_bytes = (size_t)4 * NPIX * 576 * 4;
  char* big = alloc(og_bytes);
  float* Og = (float*)big;
  size_t eoff = 0;
  auto ealloc = [&](size_t bytes) -> char* {
    char* p = big + eoff; eoff = (eoff + bytes + 255) & ~(size_t)255; return p;
  };
  float* refbuf = (float*)ealloc((size_t)2 * 64 * L_TOT * 4);
  float* mref   = (float*)ealloc((size_t)2 * 32 * L_TOT * 4);
  float* aref   = (float*)ealloc((size_t)2 * 64 * L_TOT * 4);
  float* mbb    = (float*)ealloc((size_t)2 * 32 * NPIX * 4);
  float* ssq    = (float*)ealloc((size_t)2 * L_TOT * 4);
  float* invn   = (float*)ealloc((size_t)2 * L_TOT * 4);
  // total ws ~ 89 MB

  int n1 = 2 * 64 * L_TOT;
  k_resize<<<(n1 + 255) / 256, 256, 0, stream>>>(inref, refbuf, n1);
  k_convref<<<212, 256, 0, stream>>>(refbuf, Wm, bm, Wa, ba, ap, mref, aref);
  int n3 = 2 * 32 * NPIX;
  k_mb<<<(n3 + 255) / 256, 256, 0, stream>>>(input, Wb, bb, ap, mbb, n3);
  int n4 = 2 * L_TOT;
  k_ssq<<<(n4 + 255) / 256, 256, 0, stream>>>(mref, ssq, n4);
  k_invn<<<(n4 + 255) / 256, 256, 0, stream>>>(ssq, invn, n4);
  int n4a = 2 * NPIX;
  k_ssqA<<<(n4a + 255) / 256, 256, 0, stream>>>(mbb, ssqA, n4a);
  k_m10<<<(n4a + 255) / 256, 256, 0, stream>>>(ssqA, Mlog, n4a);
  int n5 = 2 * L_PADB * 36;
  k_bim<<<(n5 + 255) / 256, 256, 0, stream>>>(mref, invn, Bm, n5);
  int n6 = 2 * NPIX * 36;
  k_aim<<<(n6 + 255) / 256, 256, 0, stream>>>(mbb, Am, n6);
  int n7 = 2 * NCHT * 576 * 4;
  k_rs<<<(n7 + 255) / 256, 256, 0, stream>>>(aref, Rs, n7);

  k_attn<<<512, 256, 0, stream>>>(Am, Bm, Rs, Mlog, Og, Ol);
  k_inv<<<(2 * NPIX + 255) / 256, 256, 0, stream>>>(Ol, inv, 2 * NPIX);
  k_final<<<256, 256, 0, stream>>>(Og, inv, input, out);
}

// Round 11
// 548.880 us; speedup vs baseline: 1.5894x; 1.2034x over previous
//
#include <hip/hip_runtime.h>
#include <stdint.h>

// PyramidAttention gfx950 — round 11: M=64 tiles to halve the L3 stream.
// 512-thread blocks (8 waves), grid 256: each block streams B+R once for 64
// pixel rows (was 32) -> ~2.95 GB total L3 traffic (was 5.9). B staged via
// global_load_lds dbuf (consumed pre-barrier but drained by PREVIOUS barrier
// - R5-safe); R triple-buffered (post-barrier readers span 2 waves/slab).
// Static row-max softmax, deferred row-sums, one barrier/chunk, 1 block/CU.

typedef __attribute__((ext_vector_type(8))) short bf16x8;
typedef __attribute__((ext_vector_type(4))) float f32x4;
typedef unsigned short ushort_t;

#define L_TOT  13326
#define NCHT   417
#define NPIX   4096
#define BCHUNK_E 9216  // 32 cols * 288 k
#define RCHUNK_E 18432 // 576 cols * 32 l
#define LOG2E10 14.4269504f   // 10*log2(e)
#define CT 256         // k_convref l-tile

__device__ __forceinline__ float cubw(float d) {
  d = fabsf(d);
  if (d <= 1.f) return (1.25f * d - 2.25f) * d * d + 1.f;          // A=-0.75
  if (d < 2.f)  return ((-0.75f * d + 3.75f) * d - 6.f) * d + 3.f;
  return 0.f;
}

__device__ __forceinline__ void decode_l(int l, int& S, int& off) {
  if (l < 4096)       { S = 64; off = 0; }
  else if (l < 7345)  { S = 57; off = 4096; }
  else if (l < 9946)  { S = 51; off = 7345; }
  else if (l < 11882) { S = 44; off = 9946; }
  else                { S = 38; off = 11882; }
}

__device__ __forceinline__ ushort_t f2bf(float f) {
  union { float f; uint32_t u; } v; v.f = f;
  uint32_t r = (v.u + 0x7fffu + ((v.u >> 16) & 1u)) >> 16;  // RNE
  return (ushort_t)r;
}

__device__ __forceinline__ float preluf(float x, float a) { return x >= 0.f ? x : a * x; }

__device__ __forceinline__ void gll16(const ushort_t* g, ushort_t* l) {
  __builtin_amdgcn_global_load_lds(
      (const __attribute__((address_space(1))) unsigned int*)g,
      (__attribute__((address_space(3))) unsigned int*)l, 16, 0, 0);
}

// ---------------- K1: bicubic resize (align_corners=True, border clamp) ----------------
__global__ void k_resize(const float* __restrict__ inref, float* __restrict__ refbuf, int n) {
  int idx = blockIdx.x * 256 + threadIdx.x;
  if (idx >= n) return;                      // n = 2*64*L_TOT, idx -> (b*64+c, l)
  int l = idx % L_TOT; int bc = idx / L_TOT;
  int S, off; decode_l(l, S, off);
  int li = l - off; int ly = li / S, lx = li % S;
  float val;
  if (S == 64) {
    val = inref[(size_t)bc * 4096 + ly * 64 + lx];
  } else {
    float sc = (float)(63.0 / (double)(S - 1));
    float sy = (float)ly * sc, sx = (float)lx * sc;
    int iy = (int)floorf(sy), ix = (int)floorf(sx);
    float fy = sy - (float)iy, fx = sx - (float)ix;
    float wy[4] = { cubw(fy + 1.f), cubw(fy), cubw(1.f - fy), cubw(2.f - fy) };
    float wx[4] = { cubw(fx + 1.f), cubw(fx), cubw(1.f - fx), cubw(2.f - fx) };
    val = 0.f;
    for (int t = 0; t < 4; ++t) {
      int ty = iy - 1 + t; ty = ty < 0 ? 0 : (ty > 63 ? 63 : ty);
      float rv = 0.f;
      for (int u = 0; u < 4; ++u) {
        int tx = ix - 1 + u; tx = tx < 0 ? 0 : (tx > 63 ? 63 : tx);
        rv += wx[u] * inref[(size_t)bc * 4096 + ty * 64 + tx];
      }
      val += wy[t] * rv;
    }
  }
  refbuf[(size_t)bc * L_TOT + l] = val;
}

// ---------------- K2: conv1x1 + prelu, LDS-tiled (refbuf read ONCE) ----------------
__global__ void k_convref(const float* __restrict__ refbuf,
                          const float* __restrict__ Wm, const float* __restrict__ bm,
                          const float* __restrict__ Wa, const float* __restrict__ ba,
                          const float* __restrict__ ap,
                          float* __restrict__ mref, float* __restrict__ aref) {
  __shared__ float T[64][CT];   // 64 KB tile: 64 in-ch x 256 l
  int blk = blockIdx.x;
  int oh = blk & 1; int lt = (blk >> 1) % 53; int b = blk / 106;
  int l0 = lt * CT;
  int tid = threadIdx.x;
  float a = ap[0];
  for (int i = tid; i < 64 * CT; i += 256) {
    int c = i >> 8; int l = i & 255;
    int gl = l0 + l;
    T[c][l] = (gl < L_TOT) ? refbuf[(size_t)(b * 64 + c) * L_TOT + gl] : 0.f;
  }
  __syncthreads();
  int gl = l0 + tid;
  if (gl >= L_TOT) return;
  for (int oc = oh * 48; oc < oh * 48 + 48; ++oc) {
    const float* Wrow; float s;
    if (oc < 32) { Wrow = Wm + oc * 64; s = bm[oc]; }
    else         { Wrow = Wa + (oc - 32) * 64; s = ba[oc - 32]; }
    #pragma unroll 8
    for (int c = 0; c < 64; ++c) s += Wrow[c] * T[c][tid];
    s = preluf(s, a);
    if (oc < 32) mref[(size_t)(b * 32 + oc) * L_TOT + gl] = s;
    else         aref[(size_t)(b * 64 + oc - 32) * L_TOT + gl] = s;
  }
}

// ---------------- K3: match_base = prelu(Wb@input+bb) ----------------
__global__ void k_mb(const float* __restrict__ input, const float* __restrict__ Wb,
                     const float* __restrict__ bb, const float* __restrict__ ap,
                     float* __restrict__ mbb, int n) {
  int idx = blockIdx.x * 256 + threadIdx.x;
  if (idx >= n) return;                      // n = 2*32*NPIX
  int p = idx % NPIX; int cm = (idx / NPIX) % 32; int b = idx / (32 * NPIX);
  float a = ap[0];
  float acc = bb[cm];
  for (int c = 0; c < 64; ++c) acc += Wb[cm * 64 + c] * input[(size_t)(b * 64 + c) * NPIX + p];
  mbb[(size_t)(b * 32 + cm) * NPIX + p] = preluf(acc, a);
}

// ---------------- K4a: per-position sum of squares of mref (key side) ----------------
__global__ void k_ssq(const float* __restrict__ mref, float* __restrict__ ssq, int n) {
  int idx = blockIdx.x * 256 + threadIdx.x;
  if (idx >= n) return;                      // n = 2*L_TOT
  int l = idx % L_TOT; int b = idx / L_TOT;
  float s = 0.f;
  for (int c = 0; c < 32; ++c) { float v = mref[(size_t)(b * 32 + c) * L_TOT + l]; s += v * v; }
  ssq[idx] = s;
}

// ---------------- K4b: 3x3 window sum -> 1/max(sqrt, 1e-4) (key norm) ----------------
__global__ void k_invn(const float* __restrict__ ssq, float* __restrict__ invn, int n) {
  int idx = blockIdx.x * 256 + threadIdx.x;
  if (idx >= n) return;
  int l = idx % L_TOT; int b = idx / L_TOT;
  int S, off; decode_l(l, S, off);
  int li = l - off; int ly = li / S, lx = li % S;
  float acc = 0.f;
  for (int dy = -1; dy <= 1; ++dy) {
    int ny = ly + dy; if (ny < 0 || ny >= S) continue;
    for (int dx = -1; dx <= 1; ++dx) {
      int nx = lx + dx; if (nx < 0 || nx >= S) continue;
      acc += ssq[(size_t)b * L_TOT + off + ny * S + nx];
    }
  }
  float nrm = sqrtf(acc); nrm = fmaxf(nrm, 1e-4f);
  invn[idx] = 1.f / nrm;
}

// ---------------- K4c: per-pixel channel ssq of match_base (query side) ----------------
__global__ void k_ssqA(const float* __restrict__ mbb, float* __restrict__ ssqA, int n) {
  int idx = blockIdx.x * 256 + threadIdx.x;
  if (idx >= n) return;                      // n = 2*NPIX
  int p = idx % NPIX; int b = idx / NPIX;
  float s = 0.f;
  for (int c = 0; c < 32; ++c) { float v = mbb[(size_t)(b * 32 + c) * NPIX + p]; s += v * v; }
  ssqA[idx] = s;
}

// ---------------- K4d: 3x3 window (zero-pad) -> static log2-domain row max ----------------
__global__ void k_m10(const float* __restrict__ ssqA, float* __restrict__ Mlog, int n) {
  int idx = blockIdx.x * 256 + threadIdx.x;
  if (idx >= n) return;                      // n = 2*NPIX
  int p = idx % NPIX; int b = idx / NPIX;
  int y = p / 64, x = p % 64;
  float acc = 0.f;
  for (int dy = -1; dy <= 1; ++dy) {
    int ny = y + dy; if (ny < 0 || ny >= 64) continue;
    for (int dx = -1; dx <= 1; ++dx) {
      int nx = x + dx; if (nx < 0 || nx >= 64) continue;
      acc += ssqA[(size_t)b * NPIX + ny * 64 + nx];
    }
  }
  float qn = sqrtf(acc);
  float m = fmaxf(0.7f * qn, qn - 7.f);
  Mlog[idx] = LOG2E10 * m;
}

// ---------------- K5: B patches -> pre-swizzled chunk blocks (R8 layout), vec8 ----------------
// Bs[b][ch][col*288 + segp*8 + e]; segl = (segp&~3)|((segp&3)^((col>>1)&3)); k = segl*8+e.
__global__ void k_bs(const float* __restrict__ mref, const float* __restrict__ invn,
                     ushort_t* __restrict__ Bs, int n) {
  int idx = blockIdx.x * 256 + threadIdx.x;
  if (idx >= n) return;                      // n = 2*NCHT*1152
  int segp = idx % 36; int col = (idx / 36) % 32;
  int ch = (idx / 1152) % NCHT; int b = idx / (1152 * NCHT);
  int segl = (segp & ~3) | ((segp & 3) ^ ((col >> 1) & 3));
  int l = ch * 32 + col;
  ushort_t v[8];
  if (l < L_TOT) {
    int S, off; decode_l(l, S, off);
    int li = l - off; int ly = li / S, lx = li % S;
    float iv = invn[(size_t)b * L_TOT + l];
    #pragma unroll
    for (int e = 0; e < 8; ++e) {
      int k = segl * 8 + e;
      int c = k / 9; int r = k % 9; int dy = r / 3 - 1, dx = r % 3 - 1;
      int ny = ly + dy, nx = lx + dx;
      float val = 0.f;
      if (ny >= 0 && ny < S && nx >= 0 && nx < S)
        val = mref[(size_t)(b * 32 + c) * L_TOT + off + ny * S + nx] * iv;
      v[e] = f2bf(val);
    }
  } else {
    #pragma unroll
    for (int e = 0; e < 8; ++e) v[e] = 0;
  }
  *(uint4*)(Bs + ((size_t)(b * NCHT + ch) * BCHUNK_E + col * 288 + segp * 8)) = *(const uint4*)v;
}

// ---------------- K6: A im2col bf16 [b][p][288], vec8 ----------------
__global__ void k_aim(const float* __restrict__ mbb, ushort_t* __restrict__ Am, int n) {
  int idx = blockIdx.x * 256 + threadIdx.x;
  if (idx >= n) return;                      // n = 2*NPIX*36
  int k8 = idx % 36; int p = (idx / 36) % NPIX; int b = idx / (36 * NPIX);
  int y = p / 64, x = p % 64;
  ushort_t v[8];
  #pragma unroll
  for (int e = 0; e < 8; ++e) {
    int k = k8 * 8 + e;
    int c = k / 9; int r = k % 9; int dy = r / 3 - 1, dx = r % 3 - 1;
    int ny = y + dy, nx = x + dx;
    float val = 0.f;
    if (ny >= 0 && ny < 64 && nx >= 0 && nx < 64)
      val = mbb[(size_t)(b * 32 + c) * NPIX + ny * 64 + nx];
    v[e] = f2bf(val);
  }
  *(uint4*)(Am + ((size_t)(b * NPIX + p) * 288 + k8 * 8)) = *(const uint4*)v;
}

// ---------------- K7: R value patches -> pre-swizzled chunk blocks, vec8 ----------------
__global__ void k_rs(const float* __restrict__ aref, ushort_t* __restrict__ Rs, int n) {
  int idx = blockIdx.x * 256 + threadIdx.x;
  if (idx >= n) return;                      // n = 2*NCHT*576*4
  int phys = idx & 3; int q = idx >> 2;
  int col = q % 576; q /= 576;
  int ch = q % NCHT; int b = q / NCHT;
  int c = col / 9; int r = col % 9; int dy = r / 3 - 1, dx = r % 3 - 1;
  int seg = phys ^ ((col >> 1) & 3);
  int lbase = ch * 32 + seg * 8;
  ushort_t v[8];
  #pragma unroll
  for (int e = 0; e < 8; ++e) {
    int l = lbase + e;
    float val = 0.f;
    if (l < L_TOT) {
      int S, off; decode_l(l, S, off);
      int li = l - off; int ly = li / S, lx = li % S;
      int ny = ly + dy, nx = lx + dx;
      if (ny >= 0 && ny < S && nx >= 0 && nx < S)
        val = aref[(size_t)(b * 64 + c) * L_TOT + off + ny * S + nx];
    }
    v[e] = f2bf(val);
  }
  *(uint4*)(Rs + ((size_t)(b * NCHT + ch) * RCHUNK_E + col * 32 + phys * 8)) = *(const uint4*)v;
}

// ---------------- K8: M=64 static-max flash attention, 512 thr, 1 block/CU ----------------
// grid 256: blockIdx -> tile(6b) | spl(1b) | b(1b). 8 waves.
// S roles: rbS = wave&3 (16-row block), cbh = wave>>2 (16-col half).
// Z roles: g = wave&3 (144-col group), zrh = wave>>2 (32-row half).
__global__ __launch_bounds__(512, 2) void k_attn(const ushort_t* __restrict__ Am,
                                                 const ushort_t* __restrict__ Bs,
                                                 const ushort_t* __restrict__ Rs,
                                                 const float* __restrict__ Mlog,
                                                 float* __restrict__ Og,
                                                 float* __restrict__ Ol) {
  __shared__ ushort_t Rl[3][RCHUNK_E];   // 110592 B: triple-buffered R chunk
  __shared__ ushort_t Bl[2][BCHUNK_E];   // 36864 B: dbuf B chunk (swizzled image)
  __shared__ ushort_t Pl[2][2048];       // 8192 B: dbuf P tile 64x32 (swizzled)
  int tid = threadIdx.x;
  int tile = blockIdx.x & 63; int spl = (blockIdx.x >> 6) & 1; int b = blockIdx.x >> 7;
  int p0 = tile * 64;
  int wave = tid >> 6, lane = tid & 63, quad = lane >> 4, ln = lane & 15;
  int rbS = wave & 3, cbh = wave >> 2;
  int g = wave & 3, zrh = wave >> 2;
  int c0 = spl ? 209 : 0, c1 = spl ? NCHT : 209;

  bf16x8 af[9];
  {
    const ushort_t* arow = Am + (size_t)(b * NPIX + p0 + rbS * 16 + ln) * 288;
    #pragma unroll
    for (int kk = 0; kk < 9; ++kk) af[kk] = *(const bf16x8*)(arow + kk * 32 + quad * 8);
  }
  float mlg[4];
  #pragma unroll
  for (int r = 0; r < 4; ++r)
    mlg[r] = Mlog[(size_t)b * NPIX + p0 + rbS * 16 + quad * 4 + r];

  f32x4 acc[2][9];
  #pragma unroll
  for (int h = 0; h < 2; ++h)
    #pragma unroll
    for (int t = 0; t < 9; ++t) { acc[h][t][0] = acc[h][t][1] = acc[h][t][2] = acc[h][t][3] = 0.f; }
  float psum[4] = {0.f, 0.f, 0.f, 0.f};

  const ushort_t* RsB = Rs + (size_t)b * NCHT * RCHUNK_E + lane * 8;
  const ushort_t* BsB = Bs + (size_t)b * NCHT * BCHUNK_E + lane * 8;

  // prologue: stage R[c0] and B[c0]; fence before first use
  {
    const ushort_t* sR = RsB + (size_t)c0 * RCHUNK_E;
    ushort_t* dR = Rl[c0 % 3];
    #pragma unroll
    for (int u = wave; u < 36; u += 8) gll16(sR + u * 512, dR + u * 512);
    const ushort_t* sB = BsB + (size_t)c0 * BCHUNK_E;
    ushort_t* dB = Bl[c0 & 1];
    #pragma unroll
    for (int u = wave; u < 18; u += 8) gll16(sB + u * 512, dB + u * 512);
  }
  __syncthreads();

  int col32 = cbh * 16 + ln;
  int bswz = (col32 >> 1) & 3;
  int rpar = c0 % 3;
  for (int ch = c0; ch < c1; ++ch) {
    int par = ch & 1;
    int cp = ch + 1 < NCHT ? ch + 1 : NCHT - 1;
    int rnext = rpar == 2 ? 0 : rpar + 1;
    // stage next chunk (B into par^1 — drained by THIS barrier, read next iter;
    // R into rnext — read next iter post-barrier; overwrite 2 barriers away)
    {
      const ushort_t* sR = RsB + (size_t)cp * RCHUNK_E;
      ushort_t* dR = Rl[rnext];
      #pragma unroll
      for (int u = wave; u < 36; u += 8) gll16(sR + u * 512, dR + u * 512);
      const ushort_t* sB = BsB + (size_t)cp * BCHUNK_E;
      ushort_t* dB = Bl[par ^ 1];
      #pragma unroll
      for (int u = wave; u < 18; u += 8) gll16(sB + u * 512, dB + u * 512);
    }
    // S-MFMA from Bl[par] (XOR-4 swizzle, R8-verified), two chains
    f32x4 sa, sb;
    sa[0] = sa[1] = sa[2] = sa[3] = 0.f;
    sb[0] = sb[1] = sb[2] = sb[3] = 0.f;
    #pragma unroll
    for (int kk = 0; kk < 9; ++kk) {
      int segp = kk * 4 + (quad ^ bswz);
      bf16x8 bf = *(const bf16x8*)&Bl[par][col32 * 288 + segp * 8];
      if (kk == 4 || kk == 5 || kk == 6 || kk == 7)
        sb = __builtin_amdgcn_mfma_f32_16x16x32_bf16(af[kk], bf, sb, 0, 0, 0);
      else
        sa = __builtin_amdgcn_mfma_f32_16x16x32_bf16(af[kk], bf, sa, 0, 0, 0);
    }
    // P = 2^(14.43*s - Mlog); write swizzled dbuf P; deferred row-sum
    int colw = ch * 32 + col32;
    bool valid = colw < L_TOT;
    #pragma unroll
    for (int r = 0; r < 4; ++r) {
      float sv = sa[r] + sb[r];
      float pv = valid ? exp2f(fmaf(sv, LOG2E10, -mlg[r])) : 0.f;
      int row = rbS * 16 + quad * 4 + r;
      int seg = cbh * 2 + (ln >> 3);
      int swz = seg ^ ((row >> 1) & 3);
      Pl[par][row * 32 + swz * 8 + (ln & 7)] = f2bf(pv);
      psum[r] += pv;
    }
    __syncthreads();   // P ready + next B/R DMA drained (only barrier per chunk)
    // Z-GEMM: P(64x32) @ R(32 x 144-per-wave) from LDS
    bf16x8 pf0, pf1;
    {
      int sw = quad ^ ((ln >> 1) & 3);
      pf0 = *(const bf16x8*)&Pl[par][(zrh * 32 + ln) * 32 + sw * 8];
      pf1 = *(const bf16x8*)&Pl[par][(zrh * 32 + 16 + ln) * 32 + sw * 8];
    }
    #pragma unroll
    for (int t = 0; t < 9; ++t) {
      int col = g * 144 + t * 16 + ln;
      int swz = quad ^ ((col >> 1) & 3);
      bf16x8 rf = *(const bf16x8*)&Rl[rpar][col * 32 + swz * 8];
      acc[0][t] = __builtin_amdgcn_mfma_f32_16x16x32_bf16(pf0, rf, acc[0][t], 0, 0, 0);
      acc[1][t] = __builtin_amdgcn_mfma_f32_16x16x32_bf16(pf1, rf, acc[1][t], 0, 0, 0);
    }
    rpar = rnext;
  }

  // epilogue: reduce deferred row-sums over the 16 lanes of each quad
  #pragma unroll
  for (int m = 1; m <= 8; m <<= 1)
    #pragma unroll
    for (int r = 0; r < 4; ++r) psum[r] += __shfl_xor(psum[r], m);
  int sb2 = spl * 2 + b;
  if (ln == 0) {
    #pragma unroll
    for (int r = 0; r < 4; ++r) {
      int row = p0 + rbS * 16 + quad * 4 + r;
      Ol[(size_t)(sb2 * 2 + cbh) * NPIX + row] = psum[r];
    }
  }
  #pragma unroll
  for (int h = 0; h < 2; ++h)
    #pragma unroll
    for (int t = 0; t < 9; ++t) {
      int colg = g * 144 + t * 16 + ln;
      #pragma unroll
      for (int r = 0; r < 4; ++r) {
        int row = p0 + zrh * 32 + h * 16 + quad * 4 + r;
        Og[((size_t)sb2 * NPIX + row) * 576 + colg] = acc[h][t][r];
      }
    }
}

// ---------------- K9: inv = 1 / sum of 4 partial row-sums ----------------
__global__ void k_inv(const float* __restrict__ Ol, float* __restrict__ inv, int n) {
  int idx = blockIdx.x * 256 + threadIdx.x;
  if (idx >= n) return;                      // n = 2*NPIX; idx = b*NPIX+p
  int b = idx / NPIX; int p = idx % NPIX;
  float s = 0.f;
  #pragma unroll
  for (int spl = 0; spl < 2; ++spl)
    #pragma unroll
    for (int cbh = 0; cbh < 2; ++cbh)
      s += Ol[(size_t)(((spl * 2 + b) * 2) + cbh) * NPIX + p];
  inv[idx] = 1.f / s;
}

// ---------------- K10: 9-tap gather, c-fastest lanes + LDS transpose, 256 blocks ----------------
__global__ void k_final(const float* __restrict__ Og, const float* __restrict__ inv,
                        const float* __restrict__ input, float* __restrict__ out) {
  __shared__ float T[32][65];
  int blk = blockIdx.x;
  int xh = blk & 1; int y = (blk >> 1) & 63; int b = blk >> 7;
  int tid = threadIdx.x;
  const size_t S1 = (size_t)2 * NPIX * 576;
  for (int it = 0; it < 8; ++it) {
    int lin = it * 256 + tid;
    int c = lin & 63, x32 = lin >> 6;
    int x = xh * 32 + x32;
    float acc = 0.f;
    for (int j = 0; j < 3; ++j) {
      int qy = y + 1 - j; if (qy < 0 || qy >= 64) continue;
      for (int i2 = 0; i2 < 3; ++i2) {
        int qx = x + 1 - i2; if (qx < 0 || qx >= 64) continue;
        int p = qy * 64 + qx;
        size_t e = ((size_t)b * NPIX + p) * 576 + c * 9 + j * 3 + i2;
        acc += (Og[e] + Og[e + S1]) * inv[b * NPIX + p];
      }
    }
    T[x32][c] = acc;
  }
  __syncthreads();
  for (int it = 0; it < 8; ++it) {
    int lin = it * 256 + tid;
    int x32 = lin & 31, c = lin >> 5;
    int o = ((b * 64 + c) * 64 + y) * 64 + xh * 32 + x32;
    out[o] = 0.25f * T[x32][c] + input[o];
  }
}

extern "C" void kernel_launch(void* const* d_in, const int* in_sizes, int n_in,
                              void* d_out, int out_size, void* d_ws, size_t ws_size,
                              hipStream_t stream) {
  (void)in_sizes; (void)n_in; (void)out_size; (void)ws_size;
  const float* input = (const float*)d_in[0];
  const float* inref = (const float*)d_in[1];
  const float* Wb = (const float*)d_in[2];
  const float* bb = (const float*)d_in[3];
  const float* Wm = (const float*)d_in[4];
  const float* bm = (const float*)d_in[5];
  const float* Wa = (const float*)d_in[6];
  const float* ba = (const float*)d_in[7];
  const float* ap = (const float*)d_in[8];
  float* out = (float*)d_out;

  char* ws = (char*)d_ws;
  size_t off = 0;
  auto alloc = [&](size_t bytes) -> char* {
    char* p = ws + off; off = (off + bytes + 255) & ~(size_t)255; return p;
  };
  // persistent region
  ushort_t* Am   = (ushort_t*)alloc((size_t)2 * NPIX * 288 * 2);        // 4.7 MB
  ushort_t* Bs   = (ushort_t*)alloc((size_t)2 * NCHT * BCHUNK_E * 2);   // 15.4 MB
  ushort_t* Rs   = (ushort_t*)alloc((size_t)2 * NCHT * RCHUNK_E * 2);   // 30.7 MB
  float*    Ol   = (float*)alloc((size_t)8 * NPIX * 4);
  float*    inv  = (float*)alloc((size_t)2 * NPIX * 4);
  float*    Mlog = (float*)alloc((size_t)2 * NPIX * 4);
  float*    ssqA = (float*)alloc((size_t)2 * NPIX * 4);
  // big region: Og (37.7 MB) aliases the early prep buffers (dead before k_attn)
  size_t og_bytes = (size_t)4 * NPIX * 576 * 4;
  char* big = alloc(og_bytes);
  float* Og = (float*)big;
  size_t eoff = 0;
  auto ealloc = [&](size_t bytes) -> char* {
    char* p = big + eoff; eoff = (eoff + bytes + 255) & ~(size_t)255; return p;
  };
  float* refbuf = (float*)ealloc((size_t)2 * 64 * L_TOT * 4);
  float* mref   = (float*)ealloc((size_t)2 * 32 * L_TOT * 4);
  float* aref   = (float*)ealloc((size_t)2 * 64 * L_TOT * 4);
  float* mbb    = (float*)ealloc((size_t)2 * 32 * NPIX * 4);
  float* ssq    = (float*)ealloc((size_t)2 * L_TOT * 4);
  float* invn   = (float*)ealloc((size_t)2 * L_TOT * 4);
  // total ws ~ 89 MB

  int n1 = 2 * 64 * L_TOT;
  k_resize<<<(n1 + 255) / 256, 256, 0, stream>>>(inref, refbuf, n1);
  k_convref<<<212, 256, 0, stream>>>(refbuf, Wm, bm, Wa, ba, ap, mref, aref);
  int n3 = 2 * 32 * NPIX;
  k_mb<<<(n3 + 255) / 256, 256, 0, stream>>>(input, Wb, bb, ap, mbb, n3);
  int n4 = 2 * L_TOT;
  k_ssq<<<(n4 + 255) / 256, 256, 0, stream>>>(mref, ssq, n4);
  k_invn<<<(n4 + 255) / 256, 256, 0, stream>>>(ssq, invn, n4);
  int n4a = 2 * NPIX;
  k_ssqA<<<(n4a + 255) / 256, 256, 0, stream>>>(mbb, ssqA, n4a);
  k_m10<<<(n4a + 255) / 256, 256, 0, stream>>>(ssqA, Mlog, n4a);
  int n5 = 2 * NCHT * 1152;
  k_bs<<<(n5 + 255) / 256, 256, 0, stream>>>(mref, invn, Bs, n5);
  int n6 = 2 * NPIX * 36;
  k_aim<<<(n6 + 255) / 256, 256, 0, stream>>>(mbb, Am, n6);
  int n7 = 2 * NCHT * 576 * 4;
  k_rs<<<(n7 + 255) / 256, 256, 0, stream>>>(aref, Rs, n7);

  k_attn<<<256, 512, 0, stream>>>(Am, Bs, Rs, Mlog, Og, Ol);
  k_inv<<<(2 * NPIX + 255) / 256, 256, 0, stream>>>(Ol, inv, 2 * NPIX);
  k_final<<<256, 256, 0, stream>>>(Og, inv, input, out);
}

// Round 12
// 527.498 us; speedup vs baseline: 1.6538x; 1.0405x over previous
//
#include <hip/hip_runtime.h>
#include <stdint.h>

// PyramidAttention gfx950 — round 12: XCD-aware swizzle in k_attn (each XCD's
// 32 blocks share one (b,spl) stream -> per-XCD L2 set 46->11.5 MB) + prep
// consolidation: bicubic fused into k_convref staging (k_resize + refbuf gone),
// ssq/ssqA and invn/m10 merged, bs/aim/rs merged -> 8 launches (was 12).
// k_attn compute structure unchanged from R11 (proven 326 us).

typedef __attribute__((ext_vector_type(8))) short bf16x8;
typedef __attribute__((ext_vector_type(4))) float f32x4;
typedef unsigned short ushort_t;

#define L_TOT  13326
#define NCHT   417
#define NPIX   4096
#define BCHUNK_E 9216  // 32 cols * 288 k
#define RCHUNK_E 18432 // 576 cols * 32 l
#define LOG2E10 14.4269504f   // 10*log2(e)
#define CT 256         // k_convref l-tile

__device__ __forceinline__ float cubw(float d) {
  d = fabsf(d);
  if (d <= 1.f) return (1.25f * d - 2.25f) * d * d + 1.f;          // A=-0.75
  if (d < 2.f)  return ((-0.75f * d + 3.75f) * d - 6.f) * d + 3.f;
  return 0.f;
}

__device__ __forceinline__ void decode_l(int l, int& S, int& off) {
  if (l < 4096)       { S = 64; off = 0; }
  else if (l < 7345)  { S = 57; off = 4096; }
  else if (l < 9946)  { S = 51; off = 7345; }
  else if (l < 11882) { S = 44; off = 9946; }
  else                { S = 38; off = 11882; }
}

__device__ __forceinline__ ushort_t f2bf(float f) {
  union { float f; uint32_t u; } v; v.f = f;
  uint32_t r = (v.u + 0x7fffu + ((v.u >> 16) & 1u)) >> 16;  // RNE
  return (ushort_t)r;
}

__device__ __forceinline__ float preluf(float x, float a) { return x >= 0.f ? x : a * x; }

__device__ __forceinline__ void gll16(const ushort_t* g, ushort_t* l) {
  __builtin_amdgcn_global_load_lds(
      (const __attribute__((address_space(1))) unsigned int*)g,
      (__attribute__((address_space(3))) unsigned int*)l, 16, 0, 0);
}

// ---------------- K2: bicubic + conv1x1 + prelu fused (refbuf eliminated) ----------------
// grid: b(2) x ltile(53) x ochalf(2) = 212 blocks, 256 threads.
__global__ void k_convref(const float* __restrict__ inref,
                          const float* __restrict__ Wm, const float* __restrict__ bm,
                          const float* __restrict__ Wa, const float* __restrict__ ba,
                          const float* __restrict__ ap,
                          float* __restrict__ mref, float* __restrict__ aref) {
  __shared__ float T[64][CT];     // 64 KB resized tile: 64 in-ch x 256 l
  __shared__ float Wy[CT][5], Wx[CT][5];   // +1 pad vs bank stride
  __shared__ int   IY[CT], IX[CT];
  int blk = blockIdx.x;
  int oh = blk & 1; int lt = (blk >> 1) % 53; int b = blk / 106;
  int l0 = lt * CT;
  int tid = threadIdx.x;
  float a = ap[0];
  // phase A: per-l bicubic params (same fp math as the reference resize)
  {
    int gl = l0 + tid;
    if (gl < L_TOT) {
      int S, off; decode_l(gl, S, off);
      int li = gl - off; int ly = li / S, lx = li % S;
      if (S == 64) {
        IY[tid] = -1; IX[tid] = ly * 64 + lx;
      } else {
        float sc = (float)(63.0 / (double)(S - 1));
        float sy = (float)ly * sc, sx = (float)lx * sc;
        int iy = (int)floorf(sy), ix = (int)floorf(sx);
        float fy = sy - (float)iy, fx = sx - (float)ix;
        IY[tid] = iy; IX[tid] = ix;
        Wy[tid][0] = cubw(fy + 1.f); Wy[tid][1] = cubw(fy);
        Wy[tid][2] = cubw(1.f - fy); Wy[tid][3] = cubw(2.f - fy);
        Wx[tid][0] = cubw(fx + 1.f); Wx[tid][1] = cubw(fx);
        Wx[tid][2] = cubw(1.f - fx); Wx[tid][3] = cubw(2.f - fx);
      }
    }
  }
  __syncthreads();
  // phase B: stage resized tile, bicubic inline (16 taps, border clamp)
  for (int i = tid; i < 64 * CT; i += 256) {
    int c = i >> 8; int l2 = i & 255;
    int gl = l0 + l2;
    float val = 0.f;
    if (gl < L_TOT) {
      const float* img = inref + (size_t)(b * 64 + c) * 4096;
      int iy = IY[l2];
      if (iy == -1) {
        val = img[IX[l2]];
      } else {
        int ix = IX[l2];
        #pragma unroll
        for (int t = 0; t < 4; ++t) {
          int ty = iy - 1 + t; ty = ty < 0 ? 0 : (ty > 63 ? 63 : ty);
          float rv = 0.f;
          #pragma unroll
          for (int u = 0; u < 4; ++u) {
            int tx = ix - 1 + u; tx = tx < 0 ? 0 : (tx > 63 ? 63 : tx);
            rv += Wx[l2][u] * img[ty * 64 + tx];
          }
          val += Wy[l2][t] * rv;
        }
      }
    }
    T[c][l2] = val;
  }
  __syncthreads();
  int gl = l0 + tid;
  if (gl >= L_TOT) return;
  for (int oc = oh * 48; oc < oh * 48 + 48; ++oc) {
    const float* Wrow; float s;
    if (oc < 32) { Wrow = Wm + oc * 64; s = bm[oc]; }
    else         { Wrow = Wa + (oc - 32) * 64; s = ba[oc - 32]; }
    #pragma unroll 8
    for (int c = 0; c < 64; ++c) s += Wrow[c] * T[c][tid];
    s = preluf(s, a);
    if (oc < 32) mref[(size_t)(b * 32 + oc) * L_TOT + gl] = s;
    else         aref[(size_t)(b * 64 + oc - 32) * L_TOT + gl] = s;
  }
}

// ---------------- K3: match_base = prelu(Wb@input+bb) ----------------
__global__ void k_mb(const float* __restrict__ input, const float* __restrict__ Wb,
                     const float* __restrict__ bb, const float* __restrict__ ap,
                     float* __restrict__ mbb, int n) {
  int idx = blockIdx.x * 256 + threadIdx.x;
  if (idx >= n) return;                      // n = 2*32*NPIX
  int p = idx % NPIX; int cm = (idx / NPIX) % 32; int b = idx / (32 * NPIX);
  float a = ap[0];
  float acc = bb[cm];
  for (int c = 0; c < 64; ++c) acc += Wb[cm * 64 + c] * input[(size_t)(b * 64 + c) * NPIX + p];
  mbb[(size_t)(b * 32 + cm) * NPIX + p] = preluf(acc, a);
}

// ---------------- K4s1: ssq (key side) U ssqA (query side), one launch ----------------
__global__ void k_stage1(const float* __restrict__ mref, const float* __restrict__ mbb,
                         float* __restrict__ ssq, float* __restrict__ ssqA, int n) {
  int idx = blockIdx.x * 256 + threadIdx.x;
  if (idx >= n) return;                      // n = 2*L_TOT + 2*NPIX
  if (idx < 2 * L_TOT) {
    int l = idx % L_TOT; int b = idx / L_TOT;
    float s = 0.f;
    for (int c = 0; c < 32; ++c) { float v = mref[(size_t)(b * 32 + c) * L_TOT + l]; s += v * v; }
    ssq[idx] = s;
  } else {
    int j = idx - 2 * L_TOT;                 // j = b*NPIX+p
    int p = j % NPIX; int b = j / NPIX;
    float s = 0.f;
    for (int c = 0; c < 32; ++c) { float v = mbb[(size_t)(b * 32 + c) * NPIX + p]; s += v * v; }
    ssqA[j] = s;
  }
}

// ---------------- K4s2: invn (key norm) U Mlog (static row max), one launch ----------------
__global__ void k_stage2(const float* __restrict__ ssq, const float* __restrict__ ssqA,
                         float* __restrict__ invn, float* __restrict__ Mlog, int n) {
  int idx = blockIdx.x * 256 + threadIdx.x;
  if (idx >= n) return;                      // n = 2*L_TOT + 2*NPIX
  if (idx < 2 * L_TOT) {
    int l = idx % L_TOT; int b = idx / L_TOT;
    int S, off; decode_l(l, S, off);
    int li = l - off; int ly = li / S, lx = li % S;
    float acc = 0.f;
    for (int dy = -1; dy <= 1; ++dy) {
      int ny = ly + dy; if (ny < 0 || ny >= S) continue;
      for (int dx = -1; dx <= 1; ++dx) {
        int nx = lx + dx; if (nx < 0 || nx >= S) continue;
        acc += ssq[(size_t)b * L_TOT + off + ny * S + nx];
      }
    }
    float nrm = sqrtf(acc); nrm = fmaxf(nrm, 1e-4f);
    invn[idx] = 1.f / nrm;
  } else {
    int j = idx - 2 * L_TOT;                 // j = b*NPIX+p
    int p = j % NPIX; int b = j / NPIX;
    int y = p / 64, x = p % 64;
    float acc = 0.f;
    for (int dy = -1; dy <= 1; ++dy) {
      int ny = y + dy; if (ny < 0 || ny >= 64) continue;
      for (int dx = -1; dx <= 1; ++dx) {
        int nx = x + dx; if (nx < 0 || nx >= 64) continue;
        acc += ssqA[(size_t)b * NPIX + ny * 64 + nx];
      }
    }
    float qn = sqrtf(acc);
    float m = fmaxf(0.7f * qn, qn - 7.f);
    Mlog[j] = LOG2E10 * m;
  }
}

// ---------------- K5/6/7 merged: Bs U Am U Rs packing, one launch, vec8 stores ----------------
#define N_BS (2 * NCHT * 1152)
#define N_AIM (2 * NPIX * 36)
#define N_RS (2 * NCHT * 576 * 4)
__global__ void k_pack(const float* __restrict__ mref, const float* __restrict__ invn,
                       const float* __restrict__ mbb, const float* __restrict__ aref,
                       ushort_t* __restrict__ Bs, ushort_t* __restrict__ Am,
                       ushort_t* __restrict__ Rs, int n) {
  int idx = blockIdx.x * 256 + threadIdx.x;
  if (idx >= n) return;                      // n = N_BS + N_AIM + N_RS
  ushort_t v[8];
  if (idx < N_BS) {
    // B patches -> pre-swizzled chunk blocks (R8 layout)
    int segp = idx % 36; int col = (idx / 36) % 32;
    int ch = (idx / 1152) % NCHT; int b = idx / (1152 * NCHT);
    int segl = (segp & ~3) | ((segp & 3) ^ ((col >> 1) & 3));
    int l = ch * 32 + col;
    if (l < L_TOT) {
      int S, off; decode_l(l, S, off);
      int li = l - off; int ly = li / S, lx = li % S;
      float iv = invn[(size_t)b * L_TOT + l];
      #pragma unroll
      for (int e = 0; e < 8; ++e) {
        int k = segl * 8 + e;
        int c = k / 9; int r = k % 9; int dy = r / 3 - 1, dx = r % 3 - 1;
        int ny = ly + dy, nx = lx + dx;
        float val = 0.f;
        if (ny >= 0 && ny < S && nx >= 0 && nx < S)
          val = mref[(size_t)(b * 32 + c) * L_TOT + off + ny * S + nx] * iv;
        v[e] = f2bf(val);
      }
    } else {
      #pragma unroll
      for (int e = 0; e < 8; ++e) v[e] = 0;
    }
    *(uint4*)(Bs + ((size_t)(b * NCHT + ch) * BCHUNK_E + col * 288 + segp * 8)) = *(const uint4*)v;
  } else if (idx < N_BS + N_AIM) {
    // A im2col
    int j = idx - N_BS;
    int k8 = j % 36; int p = (j / 36) % NPIX; int b = j / (36 * NPIX);
    int y = p / 64, x = p % 64;
    #pragma unroll
    for (int e = 0; e < 8; ++e) {
      int k = k8 * 8 + e;
      int c = k / 9; int r = k % 9; int dy = r / 3 - 1, dx = r % 3 - 1;
      int ny = y + dy, nx = x + dx;
      float val = 0.f;
      if (ny >= 0 && ny < 64 && nx >= 0 && nx < 64)
        val = mbb[(size_t)(b * 32 + c) * NPIX + ny * 64 + nx];
      v[e] = f2bf(val);
    }
    *(uint4*)(Am + ((size_t)(b * NPIX + p) * 288 + k8 * 8)) = *(const uint4*)v;
  } else {
    // R value patches -> pre-swizzled chunk blocks
    int j = idx - N_BS - N_AIM;
    int phys = j & 3; int q = j >> 2;
    int col = q % 576; q /= 576;
    int ch = q % NCHT; int b = q / NCHT;
    int c = col / 9; int r = col % 9; int dy = r / 3 - 1, dx = r % 3 - 1;
    int seg = phys ^ ((col >> 1) & 3);
    int lbase = ch * 32 + seg * 8;
    #pragma unroll
    for (int e = 0; e < 8; ++e) {
      int l = lbase + e;
      float val = 0.f;
      if (l < L_TOT) {
        int S, off; decode_l(l, S, off);
        int li = l - off; int ly = li / S, lx = li % S;
        int ny = ly + dy, nx = lx + dx;
        if (ny >= 0 && ny < S && nx >= 0 && nx < S)
          val = aref[(size_t)(b * 64 + c) * L_TOT + off + ny * S + nx];
      }
      v[e] = f2bf(val);
    }
    *(uint4*)(Rs + ((size_t)(b * NCHT + ch) * RCHUNK_E + col * 32 + phys * 8)) = *(const uint4*)v;
  }
}

// ---------------- K8: M=64 static-max flash attention + XCD-aware swizzle ----------------
// grid 256. blockIdx -> xcd = blk&7, slot = blk>>3. group = xcd>>1 (one (b,spl)
// stream per XCD pair); tile = slot*2 + (xcd&1). Bijection over (b,spl,tile).
// Compute structure identical to R11 (8 waves, R triple-buf, B dbuf, 1 barrier).
__global__ __launch_bounds__(512, 2) void k_attn(const ushort_t* __restrict__ Am,
                                                 const ushort_t* __restrict__ Bs,
                                                 const ushort_t* __restrict__ Rs,
                                                 const float* __restrict__ Mlog,
                                                 float* __restrict__ Og,
                                                 float* __restrict__ Ol) {
  __shared__ ushort_t Rl[3][RCHUNK_E];   // 110592 B: triple-buffered R chunk
  __shared__ ushort_t Bl[2][BCHUNK_E];   // 36864 B: dbuf B chunk (swizzled image)
  __shared__ ushort_t Pl[2][2048];       // 8192 B: dbuf P tile 64x32 (swizzled)
  int tid = threadIdx.x;
  int xcd = blockIdx.x & 7; int slot = blockIdx.x >> 3;
  int group = xcd >> 1;                  // 0..3 -> (spl, b)
  int spl = group & 1; int b = group >> 1;
  int tile = slot * 2 + (xcd & 1);       // 0..63
  int p0 = tile * 64;
  int wave = tid >> 6, lane = tid & 63, quad = lane >> 4, ln = lane & 15;
  int rbS = wave & 3, cbh = wave >> 2;
  int g = wave & 3, zrh = wave >> 2;
  int c0 = spl ? 209 : 0, c1 = spl ? NCHT : 209;

  bf16x8 af[9];
  {
    const ushort_t* arow = Am + (size_t)(b * NPIX + p0 + rbS * 16 + ln) * 288;
    #pragma unroll
    for (int kk = 0; kk < 9; ++kk) af[kk] = *(const bf16x8*)(arow + kk * 32 + quad * 8);
  }
  float mlg[4];
  #pragma unroll
  for (int r = 0; r < 4; ++r)
    mlg[r] = Mlog[(size_t)b * NPIX + p0 + rbS * 16 + quad * 4 + r];

  f32x4 acc[2][9];
  #pragma unroll
  for (int h = 0; h < 2; ++h)
    #pragma unroll
    for (int t = 0; t < 9; ++t) { acc[h][t][0] = acc[h][t][1] = acc[h][t][2] = acc[h][t][3] = 0.f; }
  float psum[4] = {0.f, 0.f, 0.f, 0.f};

  const ushort_t* RsB = Rs + (size_t)b * NCHT * RCHUNK_E + lane * 8;
  const ushort_t* BsB = Bs + (size_t)b * NCHT * BCHUNK_E + lane * 8;

  // prologue: stage R[c0] and B[c0]; fence before first use
  {
    const ushort_t* sR = RsB + (size_t)c0 * RCHUNK_E;
    ushort_t* dR = Rl[c0 % 3];
    #pragma unroll
    for (int u = wave; u < 36; u += 8) gll16(sR + u * 512, dR + u * 512);
    const ushort_t* sB = BsB + (size_t)c0 * BCHUNK_E;
    ushort_t* dB = Bl[c0 & 1];
    #pragma unroll
    for (int u = wave; u < 18; u += 8) gll16(sB + u * 512, dB + u * 512);
  }
  __syncthreads();

  int col32 = cbh * 16 + ln;
  int bswz = (col32 >> 1) & 3;
  int rpar = c0 % 3;
  for (int ch = c0; ch < c1; ++ch) {
    int par = ch & 1;
    int cp = ch + 1 < NCHT ? ch + 1 : NCHT - 1;
    int rnext = rpar == 2 ? 0 : rpar + 1;
    // stage next chunk (B into par^1 — drained by THIS barrier, read next iter;
    // R into rnext — read next iter post-barrier; overwrite 2 barriers away)
    {
      const ushort_t* sR = RsB + (size_t)cp * RCHUNK_E;
      ushort_t* dR = Rl[rnext];
      #pragma unroll
      for (int u = wave; u < 36; u += 8) gll16(sR + u * 512, dR + u * 512);
      const ushort_t* sB = BsB + (size_t)cp * BCHUNK_E;
      ushort_t* dB = Bl[par ^ 1];
      #pragma unroll
      for (int u = wave; u < 18; u += 8) gll16(sB + u * 512, dB + u * 512);
    }
    // S-MFMA from Bl[par] (XOR-4 swizzle, R8-verified), two chains
    f32x4 sa, sb;
    sa[0] = sa[1] = sa[2] = sa[3] = 0.f;
    sb[0] = sb[1] = sb[2] = sb[3] = 0.f;
    #pragma unroll
    for (int kk = 0; kk < 9; ++kk) {
      int segp = kk * 4 + (quad ^ bswz);
      bf16x8 bf = *(const bf16x8*)&Bl[par][col32 * 288 + segp * 8];
      if (kk == 4 || kk == 5 || kk == 6 || kk == 7)
        sb = __builtin_amdgcn_mfma_f32_16x16x32_bf16(af[kk], bf, sb, 0, 0, 0);
      else
        sa = __builtin_amdgcn_mfma_f32_16x16x32_bf16(af[kk], bf, sa, 0, 0, 0);
    }
    // P = 2^(14.43*s - Mlog); write swizzled dbuf P; deferred row-sum
    int colw = ch * 32 + col32;
    bool valid = colw < L_TOT;
    #pragma unroll
    for (int r = 0; r < 4; ++r) {
      float sv = sa[r] + sb[r];
      float pv = valid ? exp2f(fmaf(sv, LOG2E10, -mlg[r])) : 0.f;
      int row = rbS * 16 + quad * 4 + r;
      int seg = cbh * 2 + (ln >> 3);
      int swz = seg ^ ((row >> 1) & 3);
      Pl[par][row * 32 + swz * 8 + (ln & 7)] = f2bf(pv);
      psum[r] += pv;
    }
    __syncthreads();   // P ready + next B/R DMA drained (only barrier per chunk)
    // Z-GEMM: P(64x32) @ R(32 x 144-per-wave) from LDS
    bf16x8 pf0, pf1;
    {
      int sw = quad ^ ((ln >> 1) & 3);
      pf0 = *(const bf16x8*)&Pl[par][(zrh * 32 + ln) * 32 + sw * 8];
      pf1 = *(const bf16x8*)&Pl[par][(zrh * 32 + 16 + ln) * 32 + sw * 8];
    }
    #pragma unroll
    for (int t = 0; t < 9; ++t) {
      int col = g * 144 + t * 16 + ln;
      int swz = quad ^ ((col >> 1) & 3);
      bf16x8 rf = *(const bf16x8*)&Rl[rpar][col * 32 + swz * 8];
      acc[0][t] = __builtin_amdgcn_mfma_f32_16x16x32_bf16(pf0, rf, acc[0][t], 0, 0, 0);
      acc[1][t] = __builtin_amdgcn_mfma_f32_16x16x32_bf16(pf1, rf, acc[1][t], 0, 0, 0);
    }
    rpar = rnext;
  }

  // epilogue: reduce deferred row-sums over the 16 lanes of each quad
  #pragma unroll
  for (int m = 1; m <= 8; m <<= 1)
    #pragma unroll
    for (int r = 0; r < 4; ++r) psum[r] += __shfl_xor(psum[r], m);
  int sb2 = spl * 2 + b;
  if (ln == 0) {
    #pragma unroll
    for (int r = 0; r < 4; ++r) {
      int row = p0 + rbS * 16 + quad * 4 + r;
      Ol[(size_t)(sb2 * 2 + cbh) * NPIX + row] = psum[r];
    }
  }
  #pragma unroll
  for (int h = 0; h < 2; ++h)
    #pragma unroll
    for (int t = 0; t < 9; ++t) {
      int colg = g * 144 + t * 16 + ln;
      #pragma unroll
      for (int r = 0; r < 4; ++r) {
        int row = p0 + zrh * 32 + h * 16 + quad * 4 + r;
        Og[((size_t)sb2 * NPIX + row) * 576 + colg] = acc[h][t][r];
      }
    }
}

// ---------------- K9: inv = 1 / sum of 4 partial row-sums ----------------
__global__ void k_inv(const float* __restrict__ Ol, float* __restrict__ inv, int n) {
  int idx = blockIdx.x * 256 + threadIdx.x;
  if (idx >= n) return;                      // n = 2*NPIX; idx = b*NPIX+p
  int b = idx / NPIX; int p = idx % NPIX;
  float s = 0.f;
  #pragma unroll
  for (int spl = 0; spl < 2; ++spl)
    #pragma unroll
    for (int cbh = 0; cbh < 2; ++cbh)
      s += Ol[(size_t)(((spl * 2 + b) * 2) + cbh) * NPIX + p];
  inv[idx] = 1.f / s;
}

// ---------------- K10: 9-tap gather, c-fastest lanes + LDS transpose, 256 blocks ----------------
__global__ void k_final(const float* __restrict__ Og, const float* __restrict__ inv,
                        const float* __restrict__ input, float* __restrict__ out) {
  __shared__ float T[32][65];
  int blk = blockIdx.x;
  int xh = blk & 1; int y = (blk >> 1) & 63; int b = blk >> 7;
  int tid = threadIdx.x;
  const size_t S1 = (size_t)2 * NPIX * 576;
  for (int it = 0; it < 8; ++it) {
    int lin = it * 256 + tid;
    int c = lin & 63, x32 = lin >> 6;
    int x = xh * 32 + x32;
    float acc = 0.f;
    for (int j = 0; j < 3; ++j) {
      int qy = y + 1 - j; if (qy < 0 || qy >= 64) continue;
      for (int i2 = 0; i2 < 3; ++i2) {
        int qx = x + 1 - i2; if (qx < 0 || qx >= 64) continue;
        int p = qy * 64 + qx;
        size_t e = ((size_t)b * NPIX + p) * 576 + c * 9 + j * 3 + i2;
        acc += (Og[e] + Og[e + S1]) * inv[b * NPIX + p];
      }
    }
    T[x32][c] = acc;
  }
  __syncthreads();
  for (int it = 0; it < 8; ++it) {
    int lin = it * 256 + tid;
    int x32 = lin & 31, c = lin >> 5;
    int o = ((b * 64 + c) * 64 + y) * 64 + xh * 32 + x32;
    out[o] = 0.25f * T[x32][c] + input[o];
  }
}

extern "C" void kernel_launch(void* const* d_in, const int* in_sizes, int n_in,
                              void* d_out, int out_size, void* d_ws, size_t ws_size,
                              hipStream_t stream) {
  (void)in_sizes; (void)n_in; (void)out_size; (void)ws_size;
  const float* input = (const float*)d_in[0];
  const float* inref = (const float*)d_in[1];
  const float* Wb = (const float*)d_in[2];
  const float* bb = (const float*)d_in[3];
  const float* Wm = (const float*)d_in[4];
  const float* bm = (const float*)d_in[5];
  const float* Wa = (const float*)d_in[6];
  const float* ba = (const float*)d_in[7];
  const float* ap = (const float*)d_in[8];
  float* out = (float*)d_out;

  char* ws = (char*)d_ws;
  size_t off = 0;
  auto alloc = [&](size_t bytes) -> char* {
    char* p = ws + off; off = (off + bytes + 255) & ~(size_t)255; return p;
  };
  // persistent region
  ushort_t* Am   = (ushort_t*)alloc((size_t)2 * NPIX * 288 * 2);        // 4.7 MB
  ushort_t* Bs   = (ushort_t*)alloc((size_t)2 * NCHT * BCHUNK_E * 2);   // 15.4 MB
  ushort_t* Rs   = (ushort_t*)alloc((size_t)2 * NCHT * RCHUNK_E * 2);   // 30.7 MB
  float*    Ol   = (float*)alloc((size_t)8 * NPIX * 4);
  float*    inv  = (float*)alloc((size_t)2 * NPIX * 4);
  float*    Mlog = (float*)alloc((size_t)2 * NPIX * 4);
  float*    ssqA = (float*)alloc((size_t)2 * NPIX * 4);
  // big region: Og (37.7 MB) aliases the early prep buffers (dead before k_attn)
  size_t og_bytes = (size_t)4 * NPIX * 576 * 4;
  char* big = alloc(og_bytes);
  float* Og = (float*)big;
  size_t eoff = 0;
  auto ealloc = [&](size_t bytes) -> char* {
    char* p = big + eoff; eoff = (eoff + bytes + 255) & ~(size_t)255; return p;
  };
  float* mref   = (float*)ealloc((size_t)2 * 32 * L_TOT * 4);
  float* aref   = (float*)ealloc((size_t)2 * 64 * L_TOT * 4);
  float* mbb    = (float*)ealloc((size_t)2 * 32 * NPIX * 4);
  float* ssq    = (float*)ealloc((size_t)2 * L_TOT * 4);
  // total ws ~ 89 MB

  k_convref<<<212, 256, 0, stream>>>(inref, Wm, bm, Wa, ba, ap, mref, aref);
  int n3 = 2 * 32 * NPIX;
  k_mb<<<(n3 + 255) / 256, 256, 0, stream>>>(input, Wb, bb, ap, mbb, n3);
  int ns = 2 * L_TOT + 2 * NPIX;
  k_stage1<<<(ns + 255) / 256, 256, 0, stream>>>(mref, mbb, ssq, ssqA, ns);
  // invn aliases ssq? no — stage2 reads ssq; write invn into a fresh slot:
  float* invn = (float*)ealloc((size_t)2 * L_TOT * 4);
  k_stage2<<<(ns + 255) / 256, 256, 0, stream>>>(ssq, ssqA, invn, Mlog, ns);
  int np = N_BS + N_AIM + N_RS;
  k_pack<<<(np + 255) / 256, 256, 0, stream>>>(mref, invn, mbb, aref, Bs, Am, Rs, np);

  k_attn<<<256, 512, 0, stream>>>(Am, Bs, Rs, Mlog, Og, Ol);
  k_inv<<<(2 * NPIX + 255) / 256, 256, 0, stream>>>(Ol, inv, 2 * NPIX);
  k_final<<<256, 256, 0, stream>>>(Og, inv, input, out);
}

// Round 13
// 468.639 us; speedup vs baseline: 1.8615x; 1.1256x over previous
//
#include <hip/hip_runtime.h>
#include <stdint.h>

// PyramidAttention gfx950 — round 13: DMA issue point moved to just AFTER the
// barrier (was: top of loop, after Z(prev)) -> prefetch cover rises from ~S
// phase (~600 cyc) to a full chunk (~3000 cyc), removing the per-chunk
// vmcnt(0) drain stall. Stage B[ch+2] (dbuf) and R[ch+1] (tribuf) post-barrier.
// Everything else identical to R12 (XCD swizzle, consolidated prep).

typedef __attribute__((ext_vector_type(8))) short bf16x8;
typedef __attribute__((ext_vector_type(4))) float f32x4;
typedef unsigned short ushort_t;

#define L_TOT  13326
#define NCHT   417
#define NPIX   4096
#define BCHUNK_E 9216  // 32 cols * 288 k
#define RCHUNK_E 18432 // 576 cols * 32 l
#define LOG2E10 14.4269504f   // 10*log2(e)
#define CT 256         // k_convref l-tile

__device__ __forceinline__ float cubw(float d) {
  d = fabsf(d);
  if (d <= 1.f) return (1.25f * d - 2.25f) * d * d + 1.f;          // A=-0.75
  if (d < 2.f)  return ((-0.75f * d + 3.75f) * d - 6.f) * d + 3.f;
  return 0.f;
}

__device__ __forceinline__ void decode_l(int l, int& S, int& off) {
  if (l < 4096)       { S = 64; off = 0; }
  else if (l < 7345)  { S = 57; off = 4096; }
  else if (l < 9946)  { S = 51; off = 7345; }
  else if (l < 11882) { S = 44; off = 9946; }
  else                { S = 38; off = 11882; }
}

__device__ __forceinline__ ushort_t f2bf(float f) {
  union { float f; uint32_t u; } v; v.f = f;
  uint32_t r = (v.u + 0x7fffu + ((v.u >> 16) & 1u)) >> 16;  // RNE
  return (ushort_t)r;
}

__device__ __forceinline__ float preluf(float x, float a) { return x >= 0.f ? x : a * x; }

__device__ __forceinline__ void gll16(const ushort_t* g, ushort_t* l) {
  __builtin_amdgcn_global_load_lds(
      (const __attribute__((address_space(1))) unsigned int*)g,
      (__attribute__((address_space(3))) unsigned int*)l, 16, 0, 0);
}

// ---------------- K2: bicubic + conv1x1 + prelu fused ----------------
__global__ void k_convref(const float* __restrict__ inref,
                          const float* __restrict__ Wm, const float* __restrict__ bm,
                          const float* __restrict__ Wa, const float* __restrict__ ba,
                          const float* __restrict__ ap,
                          float* __restrict__ mref, float* __restrict__ aref) {
  __shared__ float T[64][CT];
  __shared__ float Wy[CT][5], Wx[CT][5];
  __shared__ int   IY[CT], IX[CT];
  int blk = blockIdx.x;
  int oh = blk & 1; int lt = (blk >> 1) % 53; int b = blk / 106;
  int l0 = lt * CT;
  int tid = threadIdx.x;
  float a = ap[0];
  {
    int gl = l0 + tid;
    if (gl < L_TOT) {
      int S, off; decode_l(gl, S, off);
      int li = gl - off; int ly = li / S, lx = li % S;
      if (S == 64) {
        IY[tid] = -1; IX[tid] = ly * 64 + lx;
      } else {
        float sc = (float)(63.0 / (double)(S - 1));
        float sy = (float)ly * sc, sx = (float)lx * sc;
        int iy = (int)floorf(sy), ix = (int)floorf(sx);
        float fy = sy - (float)iy, fx = sx - (float)ix;
        IY[tid] = iy; IX[tid] = ix;
        Wy[tid][0] = cubw(fy + 1.f); Wy[tid][1] = cubw(fy);
        Wy[tid][2] = cubw(1.f - fy); Wy[tid][3] = cubw(2.f - fy);
        Wx[tid][0] = cubw(fx + 1.f); Wx[tid][1] = cubw(fx);
        Wx[tid][2] = cubw(1.f - fx); Wx[tid][3] = cubw(2.f - fx);
      }
    }
  }
  __syncthreads();
  for (int i = tid; i < 64 * CT; i += 256) {
    int c = i >> 8; int l2 = i & 255;
    int gl = l0 + l2;
    float val = 0.f;
    if (gl < L_TOT) {
      const float* img = inref + (size_t)(b * 64 + c) * 4096;
      int iy = IY[l2];
      if (iy == -1) {
        val = img[IX[l2]];
      } else {
        int ix = IX[l2];
        #pragma unroll
        for (int t = 0; t < 4; ++t) {
          int ty = iy - 1 + t; ty = ty < 0 ? 0 : (ty > 63 ? 63 : ty);
          float rv = 0.f;
          #pragma unroll
          for (int u = 0; u < 4; ++u) {
            int tx = ix - 1 + u; tx = tx < 0 ? 0 : (tx > 63 ? 63 : tx);
            rv += Wx[l2][u] * img[ty * 64 + tx];
          }
          val += Wy[l2][t] * rv;
        }
      }
    }
    T[c][l2] = val;
  }
  __syncthreads();
  int gl = l0 + tid;
  if (gl >= L_TOT) return;
  for (int oc = oh * 48; oc < oh * 48 + 48; ++oc) {
    const float* Wrow; float s;
    if (oc < 32) { Wrow = Wm + oc * 64; s = bm[oc]; }
    else         { Wrow = Wa + (oc - 32) * 64; s = ba[oc - 32]; }
    #pragma unroll 8
    for (int c = 0; c < 64; ++c) s += Wrow[c] * T[c][tid];
    s = preluf(s, a);
    if (oc < 32) mref[(size_t)(b * 32 + oc) * L_TOT + gl] = s;
    else         aref[(size_t)(b * 64 + oc - 32) * L_TOT + gl] = s;
  }
}

// ---------------- K3: match_base = prelu(Wb@input+bb) ----------------
__global__ void k_mb(const float* __restrict__ input, const float* __restrict__ Wb,
                     const float* __restrict__ bb, const float* __restrict__ ap,
                     float* __restrict__ mbb, int n) {
  int idx = blockIdx.x * 256 + threadIdx.x;
  if (idx >= n) return;                      // n = 2*32*NPIX
  int p = idx % NPIX; int cm = (idx / NPIX) % 32; int b = idx / (32 * NPIX);
  float a = ap[0];
  float acc = bb[cm];
  for (int c = 0; c < 64; ++c) acc += Wb[cm * 64 + c] * input[(size_t)(b * 64 + c) * NPIX + p];
  mbb[(size_t)(b * 32 + cm) * NPIX + p] = preluf(acc, a);
}

// ---------------- K4s1: ssq U ssqA ----------------
__global__ void k_stage1(const float* __restrict__ mref, const float* __restrict__ mbb,
                         float* __restrict__ ssq, float* __restrict__ ssqA, int n) {
  int idx = blockIdx.x * 256 + threadIdx.x;
  if (idx >= n) return;                      // n = 2*L_TOT + 2*NPIX
  if (idx < 2 * L_TOT) {
    int l = idx % L_TOT; int b = idx / L_TOT;
    float s = 0.f;
    for (int c = 0; c < 32; ++c) { float v = mref[(size_t)(b * 32 + c) * L_TOT + l]; s += v * v; }
    ssq[idx] = s;
  } else {
    int j = idx - 2 * L_TOT;
    int p = j % NPIX; int b = j / NPIX;
    float s = 0.f;
    for (int c = 0; c < 32; ++c) { float v = mbb[(size_t)(b * 32 + c) * NPIX + p]; s += v * v; }
    ssqA[j] = s;
  }
}

// ---------------- K4s2: invn U Mlog ----------------
__global__ void k_stage2(const float* __restrict__ ssq, const float* __restrict__ ssqA,
                         float* __restrict__ invn, float* __restrict__ Mlog, int n) {
  int idx = blockIdx.x * 256 + threadIdx.x;
  if (idx >= n) return;                      // n = 2*L_TOT + 2*NPIX
  if (idx < 2 * L_TOT) {
    int l = idx % L_TOT; int b = idx / L_TOT;
    int S, off; decode_l(l, S, off);
    int li = l - off; int ly = li / S, lx = li % S;
    float acc = 0.f;
    for (int dy = -1; dy <= 1; ++dy) {
      int ny = ly + dy; if (ny < 0 || ny >= S) continue;
      for (int dx = -1; dx <= 1; ++dx) {
        int nx = lx + dx; if (nx < 0 || nx >= S) continue;
        acc += ssq[(size_t)b * L_TOT + off + ny * S + nx];
      }
    }
    float nrm = sqrtf(acc); nrm = fmaxf(nrm, 1e-4f);
    invn[idx] = 1.f / nrm;
  } else {
    int j = idx - 2 * L_TOT;
    int p = j % NPIX; int b = j / NPIX;
    int y = p / 64, x = p % 64;
    float acc = 0.f;
    for (int dy = -1; dy <= 1; ++dy) {
      int ny = y + dy; if (ny < 0 || ny >= 64) continue;
      for (int dx = -1; dx <= 1; ++dx) {
        int nx = x + dx; if (nx < 0 || nx >= 64) continue;
        acc += ssqA[(size_t)b * NPIX + ny * 64 + nx];
      }
    }
    float qn = sqrtf(acc);
    float m = fmaxf(0.7f * qn, qn - 7.f);
    Mlog[j] = LOG2E10 * m;
  }
}

// ---------------- K5/6/7 merged: Bs U Am U Rs packing, vec8 ----------------
#define N_BS (2 * NCHT * 1152)
#define N_AIM (2 * NPIX * 36)
#define N_RS (2 * NCHT * 576 * 4)
__global__ void k_pack(const float* __restrict__ mref, const float* __restrict__ invn,
                       const float* __restrict__ mbb, const float* __restrict__ aref,
                       ushort_t* __restrict__ Bs, ushort_t* __restrict__ Am,
                       ushort_t* __restrict__ Rs, int n) {
  int idx = blockIdx.x * 256 + threadIdx.x;
  if (idx >= n) return;
  ushort_t v[8];
  if (idx < N_BS) {
    int segp = idx % 36; int col = (idx / 36) % 32;
    int ch = (idx / 1152) % NCHT; int b = idx / (1152 * NCHT);
    int segl = (segp & ~3) | ((segp & 3) ^ ((col >> 1) & 3));
    int l = ch * 32 + col;
    if (l < L_TOT) {
      int S, off; decode_l(l, S, off);
      int li = l - off; int ly = li / S, lx = li % S;
      float iv = invn[(size_t)b * L_TOT + l];
      #pragma unroll
      for (int e = 0; e < 8; ++e) {
        int k = segl * 8 + e;
        int c = k / 9; int r = k % 9; int dy = r / 3 - 1, dx = r % 3 - 1;
        int ny = ly + dy, nx = lx + dx;
        float val = 0.f;
        if (ny >= 0 && ny < S && nx >= 0 && nx < S)
          val = mref[(size_t)(b * 32 + c) * L_TOT + off + ny * S + nx] * iv;
        v[e] = f2bf(val);
      }
    } else {
      #pragma unroll
      for (int e = 0; e < 8; ++e) v[e] = 0;
    }
    *(uint4*)(Bs + ((size_t)(b * NCHT + ch) * BCHUNK_E + col * 288 + segp * 8)) = *(const uint4*)v;
  } else if (idx < N_BS + N_AIM) {
    int j = idx - N_BS;
    int k8 = j % 36; int p = (j / 36) % NPIX; int b = j / (36 * NPIX);
    int y = p / 64, x = p % 64;
    #pragma unroll
    for (int e = 0; e < 8; ++e) {
      int k = k8 * 8 + e;
      int c = k / 9; int r = k % 9; int dy = r / 3 - 1, dx = r % 3 - 1;
      int ny = y + dy, nx = x + dx;
      float val = 0.f;
      if (ny >= 0 && ny < 64 && nx >= 0 && nx < 64)
        val = mbb[(size_t)(b * 32 + c) * NPIX + ny * 64 + nx];
      v[e] = f2bf(val);
    }
    *(uint4*)(Am + ((size_t)(b * NPIX + p) * 288 + k8 * 8)) = *(const uint4*)v;
  } else {
    int j = idx - N_BS - N_AIM;
    int phys = j & 3; int q = j >> 2;
    int col = q % 576; q /= 576;
    int ch = q % NCHT; int b = q / NCHT;
    int c = col / 9; int r = col % 9; int dy = r / 3 - 1, dx = r % 3 - 1;
    int seg = phys ^ ((col >> 1) & 3);
    int lbase = ch * 32 + seg * 8;
    #pragma unroll
    for (int e = 0; e < 8; ++e) {
      int l = lbase + e;
      float val = 0.f;
      if (l < L_TOT) {
        int S, off; decode_l(l, S, off);
        int li = l - off; int ly = li / S, lx = li % S;
        int ny = ly + dy, nx = lx + dx;
        if (ny >= 0 && ny < S && nx >= 0 && nx < S)
          val = aref[(size_t)(b * 64 + c) * L_TOT + off + ny * S + nx];
      }
      v[e] = f2bf(val);
    }
    *(uint4*)(Rs + ((size_t)(b * NCHT + ch) * RCHUNK_E + col * 32 + phys * 8)) = *(const uint4*)v;
  }
}

// ---------------- K8: M=64 flash attention, post-barrier DMA issue ----------------
// grid 256, XCD swizzle: xcd=blk&7, group=xcd>>1 -> (spl,b); tile=slot*2+(xcd&1).
// Loop: {S(ch); P(ch); barrier; DMA B[ch+2],R[ch+1]; Z(ch)} -> full-chunk cover.
__global__ __launch_bounds__(512, 2) void k_attn(const ushort_t* __restrict__ Am,
                                                 const ushort_t* __restrict__ Bs,
                                                 const ushort_t* __restrict__ Rs,
                                                 const float* __restrict__ Mlog,
                                                 float* __restrict__ Og,
                                                 float* __restrict__ Ol) {
  __shared__ ushort_t Rl[3][RCHUNK_E];   // 110592 B: triple-buffered R chunk
  __shared__ ushort_t Bl[2][BCHUNK_E];   // 36864 B: dbuf B chunk (swizzled image)
  __shared__ ushort_t Pl[2][2048];       // 8192 B: dbuf P tile 64x32 (swizzled)
  int tid = threadIdx.x;
  int xcd = blockIdx.x & 7; int slot = blockIdx.x >> 3;
  int group = xcd >> 1;
  int spl = group & 1; int b = group >> 1;
  int tile = slot * 2 + (xcd & 1);
  int p0 = tile * 64;
  int wave = tid >> 6, lane = tid & 63, quad = lane >> 4, ln = lane & 15;
  int rbS = wave & 3, cbh = wave >> 2;
  int g = wave & 3, zrh = wave >> 2;
  int c0 = spl ? 209 : 0, c1 = spl ? NCHT : 209;

  bf16x8 af[9];
  {
    const ushort_t* arow = Am + (size_t)(b * NPIX + p0 + rbS * 16 + ln) * 288;
    #pragma unroll
    for (int kk = 0; kk < 9; ++kk) af[kk] = *(const bf16x8*)(arow + kk * 32 + quad * 8);
  }
  float mlg[4];
  #pragma unroll
  for (int r = 0; r < 4; ++r)
    mlg[r] = Mlog[(size_t)b * NPIX + p0 + rbS * 16 + quad * 4 + r];

  f32x4 acc[2][9];
  #pragma unroll
  for (int h = 0; h < 2; ++h)
    #pragma unroll
    for (int t = 0; t < 9; ++t) { acc[h][t][0] = acc[h][t][1] = acc[h][t][2] = acc[h][t][3] = 0.f; }
  float psum[4] = {0.f, 0.f, 0.f, 0.f};

  const ushort_t* RsB = Rs + (size_t)b * NCHT * RCHUNK_E + lane * 8;
  const ushort_t* BsB = Bs + (size_t)b * NCHT * BCHUNK_E + lane * 8;

  // prologue: stage B[c0], B[c0+1], R[c0]; fence before first use
  {
    const ushort_t* sB0 = BsB + (size_t)c0 * BCHUNK_E;
    ushort_t* dB0 = Bl[c0 & 1];
    #pragma unroll
    for (int u = wave; u < 18; u += 8) gll16(sB0 + u * 512, dB0 + u * 512);
    const ushort_t* sB1 = BsB + (size_t)(c0 + 1) * BCHUNK_E;
    ushort_t* dB1 = Bl[(c0 + 1) & 1];
    #pragma unroll
    for (int u = wave; u < 18; u += 8) gll16(sB1 + u * 512, dB1 + u * 512);
    const ushort_t* sR = RsB + (size_t)c0 * RCHUNK_E;
    ushort_t* dR = Rl[c0 % 3];
    #pragma unroll
    for (int u = wave; u < 36; u += 8) gll16(sR + u * 512, dR + u * 512);
  }
  __syncthreads();

  int col32 = cbh * 16 + ln;
  int bswz = (col32 >> 1) & 3;
  int rpar = c0 % 3;
  for (int ch = c0; ch < c1; ++ch) {
    int par = ch & 1;
    int rnext = rpar == 2 ? 0 : rpar + 1;
    // S-MFMA from Bl[par] (staged 2 chunks ago, drained at previous barrier)
    f32x4 sa, sb;
    sa[0] = sa[1] = sa[2] = sa[3] = 0.f;
    sb[0] = sb[1] = sb[2] = sb[3] = 0.f;
    #pragma unroll
    for (int kk = 0; kk < 9; ++kk) {
      int segp = kk * 4 + (quad ^ bswz);
      bf16x8 bf = *(const bf16x8*)&Bl[par][col32 * 288 + segp * 8];
      if (kk == 4 || kk == 5 || kk == 6 || kk == 7)
        sb = __builtin_amdgcn_mfma_f32_16x16x32_bf16(af[kk], bf, sb, 0, 0, 0);
      else
        sa = __builtin_amdgcn_mfma_f32_16x16x32_bf16(af[kk], bf, sa, 0, 0, 0);
    }
    // P = 2^(14.43*s - Mlog); write swizzled dbuf P; deferred row-sum
    int colw = ch * 32 + col32;
    bool valid = colw < L_TOT;
    #pragma unroll
    for (int r = 0; r < 4; ++r) {
      float sv = sa[r] + sb[r];
      float pv = valid ? exp2f(fmaf(sv, LOG2E10, -mlg[r])) : 0.f;
      int row = rbS * 16 + quad * 4 + r;
      int seg = cbh * 2 + (ln >> 3);
      int swz = seg ^ ((row >> 1) & 3);
      Pl[par][row * 32 + swz * 8 + (ln & 7)] = f2bf(pv);
      psum[r] += pv;
    }
    __syncthreads();   // barrier(ch): drains DMAs issued in iteration ch-1
    // issue DMA with full-chunk cover: B[ch+2] -> Bl[par] (S(ch) done, all
    // waves past barrier), R[ch+1] -> Rl[rnext] (Z(ch-2) readers long done).
    if (ch + 2 < c1) {
      const ushort_t* sB = BsB + (size_t)(ch + 2) * BCHUNK_E;
      ushort_t* dB = Bl[par];
      #pragma unroll
      for (int u = wave; u < 18; u += 8) gll16(sB + u * 512, dB + u * 512);
    }
    if (ch + 1 < c1) {
      const ushort_t* sR = RsB + (size_t)(ch + 1) * RCHUNK_E;
      ushort_t* dR = Rl[rnext];
      #pragma unroll
      for (int u = wave; u < 36; u += 8) gll16(sR + u * 512, dR + u * 512);
    }
    // Z-GEMM: P(64x32) @ R(32 x 144-per-wave) from LDS
    bf16x8 pf0, pf1;
    {
      int sw = quad ^ ((ln >> 1) & 3);
      pf0 = *(const bf16x8*)&Pl[par][(zrh * 32 + ln) * 32 + sw * 8];
      pf1 = *(const bf16x8*)&Pl[par][(zrh * 32 + 16 + ln) * 32 + sw * 8];
    }
    #pragma unroll
    for (int t = 0; t < 9; ++t) {
      int col = g * 144 + t * 16 + ln;
      int swz = quad ^ ((col >> 1) & 3);
      bf16x8 rf = *(const bf16x8*)&Rl[rpar][col * 32 + swz * 8];
      acc[0][t] = __builtin_amdgcn_mfma_f32_16x16x32_bf16(pf0, rf, acc[0][t], 0, 0, 0);
      acc[1][t] = __builtin_amdgcn_mfma_f32_16x16x32_bf16(pf1, rf, acc[1][t], 0, 0, 0);
    }
    rpar = rnext;
  }

  // epilogue: reduce deferred row-sums over the 16 lanes of each quad
  #pragma unroll
  for (int m = 1; m <= 8; m <<= 1)
    #pragma unroll
    for (int r = 0; r < 4; ++r) psum[r] += __shfl_xor(psum[r], m);
  int sb2 = spl * 2 + b;
  if (ln == 0) {
    #pragma unroll
    for (int r = 0; r < 4; ++r) {
      int row = p0 + rbS * 16 + quad * 4 + r;
      Ol[(size_t)(sb2 * 2 + cbh) * NPIX + row] = psum[r];
    }
  }
  #pragma unroll
  for (int h = 0; h < 2; ++h)
    #pragma unroll
    for (int t = 0; t < 9; ++t) {
      int colg = g * 144 + t * 16 + ln;
      #pragma unroll
      for (int r = 0; r < 4; ++r) {
        int row = p0 + zrh * 32 + h * 16 + quad * 4 + r;
        Og[((size_t)sb2 * NPIX + row) * 576 + colg] = acc[h][t][r];
      }
    }
}

// ---------------- K9: inv = 1 / sum of 4 partial row-sums ----------------
__global__ void k_inv(const float* __restrict__ Ol, float* __restrict__ inv, int n) {
  int idx = blockIdx.x * 256 + threadIdx.x;
  if (idx >= n) return;                      // n = 2*NPIX
  int b = idx / NPIX; int p = idx % NPIX;
  float s = 0.f;
  #pragma unroll
  for (int spl = 0; spl < 2; ++spl)
    #pragma unroll
    for (int cbh = 0; cbh < 2; ++cbh)
      s += Ol[(size_t)(((spl * 2 + b) * 2) + cbh) * NPIX + p];
  inv[idx] = 1.f / s;
}

// ---------------- K10: 9-tap gather, c-fastest lanes + LDS transpose ----------------
__global__ void k_final(const float* __restrict__ Og, const float* __restrict__ inv,
                        const float* __restrict__ input, float* __restrict__ out) {
  __shared__ float T[32][65];
  int blk = blockIdx.x;
  int xh = blk & 1; int y = (blk >> 1) & 63; int b = blk >> 7;
  int tid = threadIdx.x;
  const size_t S1 = (size_t)2 * NPIX * 576;
  for (int it = 0; it < 8; ++it) {
    int lin = it * 256 + tid;
    int c = lin & 63, x32 = lin >> 6;
    int x = xh * 32 + x32;
    float acc = 0.f;
    for (int j = 0; j < 3; ++j) {
      int qy = y + 1 - j; if (qy < 0 || qy >= 64) continue;
      for (int i2 = 0; i2 < 3; ++i2) {
        int qx = x + 1 - i2; if (qx < 0 || qx >= 64) continue;
        int p = qy * 64 + qx;
        size_t e = ((size_t)b * NPIX + p) * 576 + c * 9 + j * 3 + i2;
        acc += (Og[e] + Og[e + S1]) * inv[b * NPIX + p];
      }
    }
    T[x32][c] = acc;
  }
  __syncthreads();
  for (int it = 0; it < 8; ++it) {
    int lin = it * 256 + tid;
    int x32 = lin & 31, c = lin >> 5;
    int o = ((b * 64 + c) * 64 + y) * 64 + xh * 32 + x32;
    out[o] = 0.25f * T[x32][c] + input[o];
  }
}

extern "C" void kernel_launch(void* const* d_in, const int* in_sizes, int n_in,
                              void* d_out, int out_size, void* d_ws, size_t ws_size,
                              hipStream_t stream) {
  (void)in_sizes; (void)n_in; (void)out_size; (void)ws_size;
  const float* input = (const float*)d_in[0];
  const float* inref = (const float*)d_in[1];
  const float* Wb = (const float*)d_in[2];
  const float* bb = (const float*)d_in[3];
  const float* Wm = (const float*)d_in[4];
  const float* bm = (const float*)d_in[5];
  const float* Wa = (const float*)d_in[6];
  const float* ba = (const float*)d_in[7];
  const float* ap = (const float*)d_in[8];
  float* out = (float*)d_out;

  char* ws = (char*)d_ws;
  size_t off = 0;
  auto alloc = [&](size_t bytes) -> char* {
    char* p = ws + off; off = (off + bytes + 255) & ~(size_t)255; return p;
  };
  // persistent region
  ushort_t* Am   = (ushort_t*)alloc((size_t)2 * NPIX * 288 * 2);        // 4.7 MB
  ushort_t* Bs   = (ushort_t*)alloc((size_t)2 * NCHT * BCHUNK_E * 2);   // 15.4 MB
  ushort_t* Rs   = (ushort_t*)alloc((size_t)2 * NCHT * RCHUNK_E * 2);   // 30.7 MB
  float*    Ol   = (float*)alloc((size_t)8 * NPIX * 4);
  float*    inv  = (float*)alloc((size_t)2 * NPIX * 4);
  float*    Mlog = (float*)alloc((size_t)2 * NPIX * 4);
  float*    ssqA = (float*)alloc((size_t)2 * NPIX * 4);
  // big region: Og (37.7 MB) aliases the early prep buffers
  size_t og_bytes = (size_t)4 * NPIX * 576 * 4;
  char* big = alloc(og_bytes);
  float* Og = (float*)big;
  size_t eoff = 0;
  auto ealloc = [&](size_t bytes) -> char* {
    char* p = big + eoff; eoff = (eoff + bytes + 255) & ~(size_t)255; return p;
  };
  float* mref = (float*)ealloc((size_t)2 * 32 * L_TOT * 4);
  float* aref = (float*)ealloc((size_t)2 * 64 * L_TOT * 4);
  float* mbb  = (float*)ealloc((size_t)2 * 32 * NPIX * 4);
  float* ssq  = (float*)ealloc((size_t)2 * L_TOT * 4);
  float* invn = (float*)ealloc((size_t)2 * L_TOT * 4);

  k_convref<<<212, 256, 0, stream>>>(inref, Wm, bm, Wa, ba, ap, mref, aref);
  int n3 = 2 * 32 * NPIX;
  k_mb<<<(n3 + 255) / 256, 256, 0, stream>>>(input, Wb, bb, ap, mbb, n3);
  int ns = 2 * L_TOT + 2 * NPIX;
  k_stage1<<<(ns + 255) / 256, 256, 0, stream>>>(mref, mbb, ssq, ssqA, ns);
  k_stage2<<<(ns + 255) / 256, 256, 0, stream>>>(ssq, ssqA, invn, Mlog, ns);
  int np = N_BS + N_AIM + N_RS;
  k_pack<<<(np + 255) / 256, 256, 0, stream>>>(mref, invn, mbb, aref, Bs, Am, Rs, np);

  k_attn<<<256, 512, 0, stream>>>(Am, Bs, Rs, Mlog, Og, Ol);
  k_inv<<<(2 * NPIX + 255) / 256, 256, 0, stream>>>(Ol, inv, 2 * NPIX);
  k_final<<<256, 256, 0, stream>>>(Og, inv, input, out);
}